// Round 1
// baseline (813.457 us; speedup 1.0000x reference)
//
#include <hip/hip_runtime.h>
#include <cstddef>

#define NF 8
#define NT 16384
#define ND 64
#define NK 512
#define NDK (ND * NK)      // 32768
#define NFN (NF * NT)      // 131072

// ---- workspace layout (float units) ----
static const size_t WS_T    = 0;                  // ||w_k||^2 : NF*NK = 4096
static const size_t WS_CNT  = 4096;               // counts    : NF*NK = 4096
static const size_t WS_DW   = 8192;               // dw        : NF*NDK = 262144
static const size_t WS_LOSS = 8192 + (size_t)NF * NDK;  // 270336 : 1 float
static const size_t WS_ENC  = 270340;             // enc idx (int) : NFN = 131072

// ---- output layout (float units) ----
static const size_t LOSS_OFF = (size_t)NF * NT * ND;        // 8388608
static const size_t NEWW_OFF = LOSS_OFF + 1;                // 8388609
static const size_t NCS_OFF  = NEWW_OFF + (size_t)NF * NDK; // 8650753
static const size_t NEMA_OFF = NCS_OFF + (size_t)NF * NK;   // 8654849

// ============ kernel A: t_k = sum_d w[f,d,k]^2 ============
__global__ __launch_bounds__(256) void vq_tsq(const float* __restrict__ w,
                                              float* __restrict__ t) {
    int g = blockIdx.x * 256 + threadIdx.x;   // 0..4095
    int f = g >> 9;
    int k = g & (NK - 1);
    const float* wf = w + (size_t)f * NDK + k;
    float s = 0.f;
#pragma unroll
    for (int d = 0; d < ND; ++d) {
        float v = wf[(size_t)d * NK];
        s = fmaf(v, v, s);
    }
    t[g] = s;
}

// ============ kernel B: assignment + quantized + loss partials ============
// grid: NF * 256 blocks (64 tokens each), block 256 threads
__global__ __launch_bounds__(256) void vq_assign(
    const float* __restrict__ x,    // [F,N,D]
    const float* __restrict__ w,    // [F,D,K]
    const float* __restrict__ tsq,  // [F,K]
    float* __restrict__ qout,       // d_out base (quantized region)
    int* __restrict__ enc,          // [F,N]
    float* __restrict__ loss_sum) {
    __shared__ float xT[ND][64];     // [d][token] 16 KB
    __shared__ float wl[ND][128];    // w chunk    32 KB
    __shared__ int   idx_sh[64];

    const int tid  = threadIdx.x;
    const int blk  = blockIdx.x;
    const int f    = blk >> 8;       // 256 tiles per feature
    const int tile = blk & 255;
    const int n0   = tile * 64;

    const float* xf = x + ((size_t)f * NT + n0) * ND;
    const float* wf = w + (size_t)f * NDK;
    const float* tf = tsq + (size_t)f * NK;

    // stage X tile transposed into LDS (4096 floats, 16 per thread)
    {
        int e = tid * 16;
#pragma unroll
        for (int j = 0; j < 4; ++j) {
            float4 v = *reinterpret_cast<const float4*>(xf + e + j * 4);
            int t0 = (e + j * 4) >> 6;
            int d0 = (e + j * 4) & 63;
            xT[d0 + 0][t0] = v.x;
            xT[d0 + 1][t0] = v.y;
            xT[d0 + 2][t0] = v.z;
            xT[d0 + 3][t0] = v.w;
        }
    }

    const int ti = tid >> 4;   // token group 0..15 (4 tokens each)
    const int ki = tid & 15;   // k group 0..15 (8 ks each)

    float minv[4] = {1e30f, 1e30f, 1e30f, 1e30f};
    int   mini[4] = {0, 0, 0, 0};

    for (int kc = 0; kc < 4; ++kc) {
        __syncthreads();   // protect previous chunk readers + xT visibility
        {
            // stage w[f, :, kc*128 .. +128) -> wl   (8192 floats, 32/thread)
            const float* src = wf + kc * 128;
            int m = tid * 32;
#pragma unroll
            for (int j = 0; j < 8; ++j) {
                int mm = m + j * 4;
                int d0 = mm >> 7;
                int kk = mm & 127;
                float4 v = *reinterpret_cast<const float4*>(src + (size_t)d0 * NK + kk);
                *reinterpret_cast<float4*>(&wl[d0][kk]) = v;
            }
        }
        __syncthreads();

        float acc[4][8];
#pragma unroll
        for (int t = 0; t < 4; ++t)
#pragma unroll
            for (int j = 0; j < 8; ++j) acc[t][j] = 0.f;

#pragma unroll 8
        for (int d = 0; d < ND; ++d) {
            float4 xv = *reinterpret_cast<const float4*>(&xT[d][ti * 4]);
            float4 wa = *reinterpret_cast<const float4*>(&wl[d][ki * 8]);
            float4 wb = *reinterpret_cast<const float4*>(&wl[d][ki * 8 + 4]);
            float xs[4] = {xv.x, xv.y, xv.z, xv.w};
            float wsv[8] = {wa.x, wa.y, wa.z, wa.w, wb.x, wb.y, wb.z, wb.w};
#pragma unroll
            for (int t = 0; t < 4; ++t)
#pragma unroll
                for (int j = 0; j < 8; ++j) acc[t][j] = fmaf(xs[t], wsv[j], acc[t][j]);
        }

        // fold into running argmin (k ascending per thread -> first-min tiebreak)
#pragma unroll
        for (int j = 0; j < 8; ++j) {
            int k = kc * 128 + ki * 8 + j;
            float tk = tf[k];
#pragma unroll
            for (int t = 0; t < 4; ++t) {
                float dist = fmaf(-2.f, acc[t][j], tk);
                if (dist < minv[t]) { minv[t] = dist; mini[t] = k; }
            }
        }
    }

    // cross-lane argmin across the 16 k-groups (lanes with same ti)
#pragma unroll
    for (int off = 1; off < 16; off <<= 1) {
#pragma unroll
        for (int t = 0; t < 4; ++t) {
            float ov = __shfl_xor(minv[t], off);
            int   oi = __shfl_xor(mini[t], off);
            if (ov < minv[t] || (ov == minv[t] && oi < mini[t])) {
                minv[t] = ov;
                mini[t] = oi;
            }
        }
    }
    if (ki == 0) {
#pragma unroll
        for (int t = 0; t < 4; ++t) idx_sh[ti * 4 + t] = mini[t];
    }
    __syncthreads();

    // gather quantized + loss partial. 4 threads per token, 16 d each.
    const int tt = tid >> 2;
    const int p  = tid & 3;
    int kb = idx_sh[tt];
    if (p == 0) enc[(size_t)f * NT + n0 + tt] = kb;

    float lsum = 0.f;
    float* qdst = qout + ((size_t)f * NT + n0 + tt) * ND + p * 16;
    const float* wcol = wf + kb;
#pragma unroll
    for (int qd = 0; qd < 4; ++qd) {
        float o[4];
#pragma unroll
        for (int c = 0; c < 4; ++c) {
            int d = p * 16 + qd * 4 + c;
            float qv = wcol[(size_t)d * NK];
            float xv = xT[d][tt];
            float df = qv - xv;
            lsum = fmaf(df, df, lsum);
            o[c] = qv;
        }
        *reinterpret_cast<float4*>(qdst + qd * 4) =
            make_float4(o[0], o[1], o[2], o[3]);
    }
    // wave-level loss reduction, one atomic per wave
#pragma unroll
    for (int off = 32; off > 0; off >>= 1) lsum += __shfl_xor(lsum, off);
    if ((tid & 63) == 0) atomicAdd(loss_sum, lsum);
}

// ============ kernel C: cluster histogram ============
__global__ __launch_bounds__(256) void vq_count(const int* __restrict__ enc,
                                                float* __restrict__ counts) {
    int i = blockIdx.x * 256 + threadIdx.x;
    if (i < NFN) {
        int f = i >> 14;   // N = 2^14
        atomicAdd(&counts[(size_t)f * NK + enc[i]], 1.0f);
    }
}

// ============ kernel D: dw[f,d,k] scatter-add ============
// block = 256 threads = 4 tokens x 64 lanes(d)
__global__ __launch_bounds__(256) void vq_dw(const float* __restrict__ x,
                                             const int* __restrict__ enc,
                                             float* __restrict__ dw) {
    int d  = threadIdx.x & 63;
    int g0 = blockIdx.x * 4 + (threadIdx.x >> 6);
    int stride = gridDim.x * 4;
    for (int i = g0; i < NFN; i += stride) {
        int f = i >> 14;
        int kb = enc[i];
        float v = x[(size_t)i * ND + d];
        atomicAdd(&dw[(size_t)f * NDK + (size_t)d * NK + kb], v);
    }
}

// ============ kernel E: EMA finalize ============
__global__ __launch_bounds__(256) void vq_finalize(
    const float* __restrict__ ecs,    // [F,K]
    const float* __restrict__ emaw,   // [F,D,K]
    const float* __restrict__ counts,
    const float* __restrict__ dw,
    const float* __restrict__ loss_sum,
    float* __restrict__ out) {
    __shared__ float sm[NK];
    __shared__ float wsum[4];
    const int f   = blockIdx.x;
    const int tid = threadIdx.x;

    float local = 0.f;
#pragma unroll
    for (int j = 0; j < 2; ++j) {
        int k = tid + j * 256;
        float c = counts[(size_t)f * NK + k];
        float v = 0.99f * ecs[(size_t)f * NK + k] + 0.01f * c;
        out[NCS_OFF + (size_t)f * NK + k] = v;
        sm[k] = v;        // temp: new_cluster_size
        local += v;
    }
    // block reduction for n
#pragma unroll
    for (int off = 32; off > 0; off >>= 1) local += __shfl_xor(local, off);
    if ((tid & 63) == 0) wsum[tid >> 6] = local;
    __syncthreads();
    float n = wsum[0] + wsum[1] + wsum[2] + wsum[3];

    // smoothed = (ncs + eps) / (n + K*eps) * n
#pragma unroll
    for (int j = 0; j < 2; ++j) {
        int k = tid + j * 256;
        sm[k] = (sm[k] + 1e-5f) / (n + (float)NK * 1e-5f) * n;
    }
    __syncthreads();

    for (int m = tid; m < NDK; m += 256) {
        int k = m & (NK - 1);
        float dwv = dw[(size_t)f * NDK + m];
        float ew  = emaw[(size_t)f * NDK + m];
        float ne  = 0.99f * ew + 0.01f * dwv;
        out[NEMA_OFF + (size_t)f * NDK + m] = ne;
        out[NEWW_OFF + (size_t)f * NDK + m] = ne / sm[k];
    }

    if (f == 0 && tid == 0) {
        out[LOSS_OFF] = 0.25f * loss_sum[0] / (float)((size_t)NF * NT * ND);
    }
}

extern "C" void kernel_launch(void* const* d_in, const int* in_sizes, int n_in,
                              void* d_out, int out_size, void* d_ws, size_t ws_size,
                              hipStream_t stream) {
    const float* x    = (const float*)d_in[0];
    const float* w    = (const float*)d_in[1];
    const float* ecs  = (const float*)d_in[2];
    const float* emaw = (const float*)d_in[3];
    float* out = (float*)d_out;
    float* ws  = (float*)d_ws;

    float* t      = ws + WS_T;
    float* counts = ws + WS_CNT;
    float* dw     = ws + WS_DW;
    float* loss   = ws + WS_LOSS;
    int*   enc    = (int*)(ws + WS_ENC);

    // zero counts + dw + loss in one async memset (capture-safe)
    hipMemsetAsync(counts, 0, (size_t)(NF * NK + NF * NDK + 1) * sizeof(float), stream);

    vq_tsq<<<16, 256, 0, stream>>>(w, t);
    vq_assign<<<NF * 256, 256, 0, stream>>>(x, w, t, out, enc, loss);
    vq_count<<<NFN / 256, 256, 0, stream>>>(enc, counts);
    vq_dw<<<2048, 256, 0, stream>>>(x, enc, dw);
    vq_finalize<<<NF, 256, 0, stream>>>(ecs, emaw, counts, dw, loss, out);
}

// Round 4
// 413.847 us; speedup vs baseline: 1.9656x; 1.9656x over previous
//
#include <hip/hip_runtime.h>
#include <cstddef>

#define NF 8
#define NT 16384
#define ND 64
#define NK 512
#define NDK (ND * NK)      // 32768
#define NFN (NF * NT)      // 131072

// ---- workspace layout (float units) ----
static const size_t WS_CNT  = 0;        // counts      : NF*NK = 4096 floats
static const size_t WS_LOSS = 4096;     // loss accum  : 1 float
static const size_t WS_T    = 4112;     // ||w_k||^2   : 4096 floats
static const size_t WS_SM   = 8208;     // smoothed    : 4096 floats
static const size_t WS_OFFS = 12304;    // offsets     : 4096 ints
static const size_t WS_CUR  = 16400;    // cursors     : 4096 ints
static const size_t WS_ENC  = 20496;    // enc idx     : NFN ints
static const size_t WS_SORT = 151568;   // sorted tok  : NFN ints

// ---- output layout (float units) ----
static const size_t LOSS_OFF = (size_t)NF * NT * ND;        // 8388608
static const size_t NEWW_OFF = LOSS_OFF + 1;                // 8388609
static const size_t NCS_OFF  = NEWW_OFF + (size_t)NF * NDK; // 8650753
static const size_t NEMA_OFF = NCS_OFF + (size_t)NF * NK;   // 8654849

// ============ kernel A: t_k = sum_d w[f,d,k]^2 ============
__global__ __launch_bounds__(256) void vq_tsq(const float* __restrict__ w,
                                              float* __restrict__ t) {
    int g = blockIdx.x * 256 + threadIdx.x;   // 0..4095
    int f = g >> 9;
    int k = g & (NK - 1);
    const float* wf = w + (size_t)f * NDK + k;
    float s = 0.f;
#pragma unroll
    for (int d = 0; d < ND; ++d) {
        float v = wf[(size_t)d * NK];
        s = fmaf(v, v, s);
    }
    t[g] = s;
}

// ============ kernel B: assignment + quantized + loss + counts ============
// grid: NF * 256 blocks (64 tokens each), block 256 threads
__global__ __launch_bounds__(256) void vq_assign(
    const float* __restrict__ x,    // [F,N,D]
    const float* __restrict__ w,    // [F,D,K]
    const float* __restrict__ tsq,  // [F,K]
    float* __restrict__ qout,       // d_out base (quantized region)
    int* __restrict__ enc,          // [F,N]
    float* __restrict__ counts,     // [F,K]
    float* __restrict__ loss_sum) {
    __shared__ float xT[ND][64];     // [d][token] 16 KB
    __shared__ float wl[ND][128];    // w chunk    32 KB
    __shared__ int   idx_sh[64];

    const int tid  = threadIdx.x;
    const int blk  = blockIdx.x;
    const int f    = blk >> 8;       // 256 tiles per feature
    const int tile = blk & 255;
    const int n0   = tile * 64;

    const float* xf = x + ((size_t)f * NT + n0) * ND;
    const float* wf = w + (size_t)f * NDK;
    const float* tf = tsq + (size_t)f * NK;

    // stage X tile transposed into LDS (4096 floats, 16 per thread)
    {
        int e = tid * 16;
#pragma unroll
        for (int j = 0; j < 4; ++j) {
            float4 v = *reinterpret_cast<const float4*>(xf + e + j * 4);
            int t0 = (e + j * 4) >> 6;
            int d0 = (e + j * 4) & 63;
            xT[d0 + 0][t0] = v.x;
            xT[d0 + 1][t0] = v.y;
            xT[d0 + 2][t0] = v.z;
            xT[d0 + 3][t0] = v.w;
        }
    }

    const int ti = tid >> 4;   // token group 0..15 (4 tokens each)
    const int ki = tid & 15;   // k group 0..15 (8 ks each)

    float minv[4] = {1e30f, 1e30f, 1e30f, 1e30f};
    int   mini[4] = {0, 0, 0, 0};

    for (int kc = 0; kc < 4; ++kc) {
        __syncthreads();   // protect previous chunk readers + xT visibility
        {
            // stage w[f, :, kc*128 .. +128) -> wl   (8192 floats, 32/thread)
            const float* src = wf + kc * 128;
            int m = tid * 32;
#pragma unroll
            for (int j = 0; j < 8; ++j) {
                int mm = m + j * 4;
                int d0 = mm >> 7;
                int kk = mm & 127;
                float4 v = *reinterpret_cast<const float4*>(src + (size_t)d0 * NK + kk);
                *reinterpret_cast<float4*>(&wl[d0][kk]) = v;
            }
        }
        __syncthreads();

        float acc[4][8];
#pragma unroll
        for (int t = 0; t < 4; ++t)
#pragma unroll
            for (int j = 0; j < 8; ++j) acc[t][j] = 0.f;

#pragma unroll 8
        for (int d = 0; d < ND; ++d) {
            float4 xv = *reinterpret_cast<const float4*>(&xT[d][ti * 4]);
            float4 wa = *reinterpret_cast<const float4*>(&wl[d][ki * 8]);
            float4 wb = *reinterpret_cast<const float4*>(&wl[d][ki * 8 + 4]);
            float xs[4] = {xv.x, xv.y, xv.z, xv.w};
            float wsv[8] = {wa.x, wa.y, wa.z, wa.w, wb.x, wb.y, wb.z, wb.w};
#pragma unroll
            for (int t = 0; t < 4; ++t)
#pragma unroll
                for (int j = 0; j < 8; ++j) acc[t][j] = fmaf(xs[t], wsv[j], acc[t][j]);
        }

        // fold into running argmin (k ascending per thread -> first-min tiebreak)
#pragma unroll
        for (int j = 0; j < 8; ++j) {
            int k = kc * 128 + ki * 8 + j;
            float tk = tf[k];
#pragma unroll
            for (int t = 0; t < 4; ++t) {
                float dist = fmaf(-2.f, acc[t][j], tk);
                if (dist < minv[t]) { minv[t] = dist; mini[t] = k; }
            }
        }
    }

    // cross-lane argmin across the 16 k-groups (lanes with same ti)
#pragma unroll
    for (int off = 1; off < 16; off <<= 1) {
#pragma unroll
        for (int t = 0; t < 4; ++t) {
            float ov = __shfl_xor(minv[t], off);
            int   oi = __shfl_xor(mini[t], off);
            if (ov < minv[t] || (ov == minv[t] && oi < mini[t])) {
                minv[t] = ov;
                mini[t] = oi;
            }
        }
    }
    if (ki == 0) {
#pragma unroll
        for (int t = 0; t < 4; ++t) idx_sh[ti * 4 + t] = mini[t];
    }
    __syncthreads();

    // gather quantized + loss partial + counts. 4 threads per token, 16 d each.
    const int tt = tid >> 2;
    const int p  = tid & 3;
    int kb = idx_sh[tt];
    if (p == 0) {
        enc[(size_t)f * NT + n0 + tt] = kb;
        atomicAdd(&counts[(size_t)f * NK + kb], 1.0f);
    }

    float lsum = 0.f;
    float* qdst = qout + ((size_t)f * NT + n0 + tt) * ND + p * 16;
    const float* wcol = wf + kb;
#pragma unroll
    for (int qd = 0; qd < 4; ++qd) {
        float o[4];
#pragma unroll
        for (int c = 0; c < 4; ++c) {
            int d = p * 16 + qd * 4 + c;
            float qv = wcol[(size_t)d * NK];
            float xv = xT[d][tt];
            float df = qv - xv;
            lsum = fmaf(df, df, lsum);
            o[c] = qv;
        }
        *reinterpret_cast<float4*>(qdst + qd * 4) =
            make_float4(o[0], o[1], o[2], o[3]);
    }
    // wave-level loss reduction, one atomic per wave
#pragma unroll
    for (int off = 32; off > 0; off >>= 1) lsum += __shfl_xor(lsum, off);
    if ((tid & 63) == 0) atomicAdd(loss_sum, lsum);
}

// ============ kernel C: per-feature exclusive scan of counts ============
// grid: NF blocks, 256 threads, 2 counts per thread
__global__ __launch_bounds__(256) void vq_scan(const float* __restrict__ counts,
                                               int* __restrict__ offs,
                                               int* __restrict__ cursor) {
    __shared__ int wsum[4];
    __shared__ int wpre[4];
    const int f = blockIdx.x, tid = threadIdx.x;
    int c0 = (int)counts[(size_t)f * NK + 2 * tid];
    int c1 = (int)counts[(size_t)f * NK + 2 * tid + 1];
    int pair = c0 + c1;
    int s = pair;
    int lane = tid & 63, wid = tid >> 6;
#pragma unroll
    for (int off = 1; off < 64; off <<= 1) {
        int v = __shfl_up(s, off);
        if (lane >= off) s += v;
    }
    if (lane == 63) wsum[wid] = s;
    __syncthreads();
    if (tid == 0) {
        int r = 0;
#pragma unroll
        for (int i = 0; i < 4; ++i) { wpre[i] = r; r += wsum[i]; }
    }
    __syncthreads();
    int excl = wpre[wid] + s - pair;     // exclusive prefix of this thread's pair
    int i0 = f * NK + 2 * tid;
    offs[i0] = excl;        offs[i0 + 1] = excl + c0;
    cursor[i0] = excl;      cursor[i0 + 1] = excl + c0;
}

// ============ kernel D: scatter token ids into cluster-sorted order ============
__global__ __launch_bounds__(256) void vq_scatter(const int* __restrict__ enc,
                                                  int* __restrict__ cursor,
                                                  int* __restrict__ sorted) {
    int i = blockIdx.x * 256 + threadIdx.x;
    if (i < NFN) {
        int f = i >> 14;
        int n = i & (NT - 1);
        int k = enc[i];
        int pos = atomicAdd(&cursor[f * NK + k], 1);
        sorted[(f << 14) + pos] = n;
    }
}

// ============ kernel E: new_cluster_size + smoothed + loss scalar ============
__global__ __launch_bounds__(256) void vq_smooth(const float* __restrict__ ecs,
                                                 const float* __restrict__ counts,
                                                 const float* __restrict__ loss_sum,
                                                 float* __restrict__ smoothed,
                                                 float* __restrict__ out) {
    __shared__ float wsum[4];
    const int f = blockIdx.x, tid = threadIdx.x;
    float v[2];
    float local = 0.f;
#pragma unroll
    for (int j = 0; j < 2; ++j) {
        int k = tid + j * 256;
        float c = counts[(size_t)f * NK + k];
        float nv = 0.99f * ecs[(size_t)f * NK + k] + 0.01f * c;
        out[NCS_OFF + (size_t)f * NK + k] = nv;
        v[j] = nv;
        local += nv;
    }
#pragma unroll
    for (int off = 32; off > 0; off >>= 1) local += __shfl_xor(local, off);
    if ((tid & 63) == 0) wsum[tid >> 6] = local;
    __syncthreads();
    float n = wsum[0] + wsum[1] + wsum[2] + wsum[3];
#pragma unroll
    for (int j = 0; j < 2; ++j) {
        int k = tid + j * 256;
        smoothed[(size_t)f * NK + k] = (v[j] + 1e-5f) / (n + (float)NK * 1e-5f) * n;
    }
    if (f == 0 && tid == 0) {
        out[LOSS_OFF] = 0.25f * loss_sum[0] / (float)((size_t)NF * NT * ND);
    }
}

// ============ kernel F: segmented sum -> dw column + fused EMA outputs ============
// grid: NF*NK blocks (one per (f,k)), 256 threads = 4 waves splitting the segment
__global__ __launch_bounds__(256) void vq_dwsum(const float* __restrict__ x,
                                                const int* __restrict__ sorted,
                                                const int* __restrict__ offs,
                                                const float* __restrict__ counts,
                                                const float* __restrict__ emaw,
                                                const float* __restrict__ smoothed,
                                                float* __restrict__ out) {
    __shared__ float part[4][64];
    const int b = blockIdx.x;          // f*NK + k
    const int f = b >> 9;
    const int k = b & (NK - 1);
    const int wid = threadIdx.x >> 6;
    const int d = threadIdx.x & 63;

    const int off = offs[b];
    const int cnt = (int)counts[b];
    const float* xf = x + (((size_t)f << 14) * ND);
    const int* sl = sorted + ((size_t)f << 14) + off;

    int per = (cnt + 3) >> 2;
    int t0 = wid * per;
    int t1 = t0 + per; if (t1 > cnt) t1 = cnt; if (t0 > cnt) t0 = cnt;

    float a0 = 0.f, a1 = 0.f;
    int t = t0;
    for (; t + 2 <= t1; t += 2) {
        int n0 = sl[t];
        int n1 = sl[t + 1];
        a0 += xf[(size_t)n0 * ND + d];
        a1 += xf[(size_t)n1 * ND + d];
    }
    if (t < t1) a0 += xf[(size_t)sl[t] * ND + d];
    part[wid][d] = a0 + a1;
    __syncthreads();

    if (wid == 0) {
        float dwv = part[0][d] + part[1][d] + part[2][d] + part[3][d];
        size_t idx = (size_t)f * NDK + (size_t)d * NK + k;
        float ne = 0.99f * emaw[idx] + 0.01f * dwv;
        out[NEMA_OFF + idx] = ne;
        out[NEWW_OFF + idx] = ne / smoothed[b];
    }
}

extern "C" void kernel_launch(void* const* d_in, const int* in_sizes, int n_in,
                              void* d_out, int out_size, void* d_ws, size_t ws_size,
                              hipStream_t stream) {
    const float* x    = (const float*)d_in[0];
    const float* w    = (const float*)d_in[1];
    const float* ecs  = (const float*)d_in[2];
    const float* emaw = (const float*)d_in[3];
    float* out = (float*)d_out;
    float* ws  = (float*)d_ws;

    float* counts = ws + WS_CNT;
    float* loss   = ws + WS_LOSS;
    float* t      = ws + WS_T;
    float* sm     = ws + WS_SM;
    int*   offs   = (int*)(ws + WS_OFFS);
    int*   cursor = (int*)(ws + WS_CUR);
    int*   enc    = (int*)(ws + WS_ENC);
    int*   sorted = (int*)(ws + WS_SORT);

    // zero counts + loss (capture-safe)
    hipMemsetAsync(counts, 0, (size_t)4112 * sizeof(float), stream);

    vq_tsq<<<16, 256, 0, stream>>>(w, t);
    vq_assign<<<NF * 256, 256, 0, stream>>>(x, w, t, out, enc, counts, loss);
    vq_scan<<<NF, 256, 0, stream>>>(counts, offs, cursor);
    vq_scatter<<<NFN / 256, 256, 0, stream>>>(enc, cursor, sorted);
    vq_smooth<<<NF, 256, 0, stream>>>(ecs, counts, loss, sm, out);
    vq_dwsum<<<NF * NK, 256, 0, stream>>>(x, sorted, offs, counts, emaw, sm, out);
}

// Round 5
// 348.960 us; speedup vs baseline: 2.3311x; 1.1859x over previous
//
#include <hip/hip_runtime.h>
#include <cstddef>

#define NF 8
#define NT 16384
#define ND 64
#define NK 512
#define NDK (ND * NK)      // 32768
#define NFN (NF * NT)      // 131072

// ---- workspace layout (float units) ----
static const size_t WS_CNT  = 0;        // counts      : NF*NK = 4096 floats
static const size_t WS_LOSS = 4096;     // loss accum  : 1 float
static const size_t WS_T    = 4112;     // ||w_k||^2   : 4096 floats
static const size_t WS_SM   = 8208;     // smoothed    : 4096 floats
static const size_t WS_OFFS = 12304;    // offsets     : 4096 ints
static const size_t WS_CUR  = 16400;    // cursors     : 4096 ints
static const size_t WS_ENC  = 20496;    // enc idx     : NFN ints
static const size_t WS_SORT = 151568;   // sorted tok  : NFN ints

// ---- output layout (float units) ----
static const size_t LOSS_OFF = (size_t)NF * NT * ND;        // 8388608
static const size_t NEWW_OFF = LOSS_OFF + 1;                // 8388609
static const size_t NCS_OFF  = NEWW_OFF + (size_t)NF * NDK; // 8650753
static const size_t NEMA_OFF = NCS_OFF + (size_t)NF * NK;   // 8654849

// ============ kernel A: t_k = sum_d w[f,d,k]^2 ============
__global__ __launch_bounds__(256) void vq_tsq(const float* __restrict__ w,
                                              float* __restrict__ t) {
    int g = blockIdx.x * 256 + threadIdx.x;   // 0..4095
    int f = g >> 9;
    int k = g & (NK - 1);
    const float* wf = w + (size_t)f * NDK + k;
    float s = 0.f;
#pragma unroll
    for (int d = 0; d < ND; ++d) {
        float v = wf[(size_t)d * NK];
        s = fmaf(v, v, s);
    }
    t[g] = s;
}

// ============ kernel B: argmin assignment (pure GEMM + argmin) ============
// grid: NF*128 blocks (128 tokens each), 256 threads.
// Wave tile: 64 tokens x 64 ks; thread tile 8x8.
// 4 waves = (token-half wt) x (k-half wk) of a 128tok x 128k chunk tile.
// Distance math (fmaf chain over d, fmaf(-2,acc,tsq), first-min tiebreak)
// is bitwise-identical to the previous passing kernel.
__global__ __launch_bounds__(256, 2) void vq_assign(
    const float* __restrict__ x,    // [F,N,D]
    const float* __restrict__ w,    // [F,D,K]
    const float* __restrict__ tsq,  // [F,K]
    int* __restrict__ enc,          // [F,N]
    float* __restrict__ counts) {   // [F,K]
    __shared__ float xT[ND][128];   // [d][token] 32 KB, conflict-free
    __shared__ float wl[ND][128];   // w chunk    32 KB, conflict-free

    const int tid = threadIdx.x;
    const int blk = blockIdx.x;
    const int f   = blk >> 7;        // 128 blocks per feature
    const int n0  = (blk & 127) * 128;

    const float* xf = x + ((size_t)f * NT + n0) * ND;
    const float* wf = w + (size_t)f * NDK;
    const float* tf = tsq + (size_t)f * NK;

    // ---- stage xT (transpose): thread t=tid>>1, d-half=(tid&1)*32 ----
    // global: 2 threads cover one 256B token row (coalesced float4).
    // LDS write bank = (d*128 + t)%32 = t%32 -> 2 words/bank = floor.
    {
        const int t  = tid >> 1;
        const int dh = (tid & 1) * 32;
        const float* src = xf + (size_t)t * ND + dh;
#pragma unroll
        for (int j = 0; j < 8; ++j) {
            float4 v = *reinterpret_cast<const float4*>(src + j * 4);
            xT[dh + j * 4 + 0][t] = v.x;
            xT[dh + j * 4 + 1][t] = v.y;
            xT[dh + j * 4 + 2][t] = v.z;
            xT[dh + j * 4 + 3][t] = v.w;
        }
    }

    const int lane = tid & 63;
    const int wid  = tid >> 6;
    const int wt   = wid & 1;        // token half
    const int wk   = wid >> 1;       // k half
    const int tg   = lane & 7;
    const int kg   = lane >> 3;
    const int tb   = wt * 64 + tg * 8;   // first token (of 8)
    const int kb   = wk * 64 + kg * 8;   // first k within chunk (of 8)

    float minv[8];
    int   mini[8];
#pragma unroll
    for (int i = 0; i < 8; ++i) { minv[i] = 1e30f; mini[i] = 0; }

    // staging mapping for wl: k-major so banks spread (8 words/bank floor)
    const int kq = tid & 31;         // k quad: k = kq*4
    const int dg = tid >> 5;         // d group: rows dg*8 .. +7

    for (int kc = 0; kc < 4; ++kc) {
        __syncthreads();   // previous chunk fully consumed
        {
            const float* src = wf + kc * 128 + kq * 4;
#pragma unroll
            for (int r = 0; r < 8; ++r) {
                int d = dg * 8 + r;
                float4 v = *reinterpret_cast<const float4*>(src + (size_t)d * NK);
                *reinterpret_cast<float4*>(&wl[d][kq * 4]) = v;
            }
        }
        __syncthreads();

        float acc[8][8];
#pragma unroll
        for (int i = 0; i < 8; ++i)
#pragma unroll
            for (int j = 0; j < 8; ++j) acc[i][j] = 0.f;

#pragma unroll 2
        for (int d = 0; d < ND; ++d) {
            float4 xa = *reinterpret_cast<const float4*>(&xT[d][tb]);
            float4 xb = *reinterpret_cast<const float4*>(&xT[d][tb + 4]);
            float4 wa = *reinterpret_cast<const float4*>(&wl[d][kb]);
            float4 wb = *reinterpret_cast<const float4*>(&wl[d][kb + 4]);
            float xs[8] = {xa.x, xa.y, xa.z, xa.w, xb.x, xb.y, xb.z, xb.w};
            float wv[8] = {wa.x, wa.y, wa.z, wa.w, wb.x, wb.y, wb.z, wb.w};
#pragma unroll
            for (int i = 0; i < 8; ++i)
#pragma unroll
                for (int j = 0; j < 8; ++j)
                    acc[i][j] = fmaf(xs[i], wv[j], acc[i][j]);
        }

        // fold into running argmin (thread's ks ascending -> first-min)
#pragma unroll
        for (int j = 0; j < 8; ++j) {
            int k = kc * 128 + kb + j;
            float tk = tf[k];
#pragma unroll
            for (int i = 0; i < 8; ++i) {
                float dist = fmaf(-2.f, acc[i][j], tk);
                if (dist < minv[i]) { minv[i] = dist; mini[i] = k; }
            }
        }
    }

    // cross-lane argmin across kg (lanes xor 8,16,32), lower-k tiebreak
#pragma unroll
    for (int off = 8; off < 64; off <<= 1) {
#pragma unroll
        for (int i = 0; i < 8; ++i) {
            float ov = __shfl_xor(minv[i], off);
            int   oi = __shfl_xor(mini[i], off);
            if (ov < minv[i] || (ov == minv[i] && oi < mini[i])) {
                minv[i] = ov;
                mini[i] = oi;
            }
        }
    }

    // cross-wave (wk halves) merge via LDS (reuse wl storage)
    float* red_v = &wl[0][0];                      // [wk*128 + t]
    int*   red_i = reinterpret_cast<int*>(&wl[2][0]);
    __syncthreads();   // all wl reads done before overwrite
    if (kg == 0) {
#pragma unroll
        for (int i = 0; i < 8; ++i) {
            red_v[wk * 128 + tb + i] = minv[i];
            red_i[wk * 128 + tb + i] = mini[i];
        }
    }
    __syncthreads();
    if (tid < 128) {
        float v0 = red_v[tid], v1 = red_v[128 + tid];
        int   i0 = red_i[tid], i1 = red_i[128 + tid];
        bool take1 = (v1 < v0) || (v1 == v0 && i1 < i0);
        int kf = take1 ? i1 : i0;
        enc[(size_t)f * NT + n0 + tid] = kf;
        atomicAdd(&counts[(size_t)f * NK + kf], 1.0f);
    }
}

// ============ kernel C: per-feature exclusive scan of counts ============
__global__ __launch_bounds__(256) void vq_scan(const float* __restrict__ counts,
                                               int* __restrict__ offs,
                                               int* __restrict__ cursor) {
    __shared__ int wsum[4];
    __shared__ int wpre[4];
    const int f = blockIdx.x, tid = threadIdx.x;
    int c0 = (int)counts[(size_t)f * NK + 2 * tid];
    int c1 = (int)counts[(size_t)f * NK + 2 * tid + 1];
    int pair = c0 + c1;
    int s = pair;
    int lane = tid & 63, wid = tid >> 6;
#pragma unroll
    for (int off = 1; off < 64; off <<= 1) {
        int v = __shfl_up(s, off);
        if (lane >= off) s += v;
    }
    if (lane == 63) wsum[wid] = s;
    __syncthreads();
    if (tid == 0) {
        int r = 0;
#pragma unroll
        for (int i = 0; i < 4; ++i) { wpre[i] = r; r += wsum[i]; }
    }
    __syncthreads();
    int excl = wpre[wid] + s - pair;
    int i0 = f * NK + 2 * tid;
    offs[i0] = excl;        offs[i0 + 1] = excl + c0;
    cursor[i0] = excl;      cursor[i0 + 1] = excl + c0;
}

// ============ kernel D: scatter token ids into cluster-sorted order ============
__global__ __launch_bounds__(256) void vq_scatter(const int* __restrict__ enc,
                                                  int* __restrict__ cursor,
                                                  int* __restrict__ sorted) {
    int i = blockIdx.x * 256 + threadIdx.x;
    if (i < NFN) {
        int f = i >> 14;
        int n = i & (NT - 1);
        int k = enc[i];
        int pos = atomicAdd(&cursor[f * NK + k], 1);
        sorted[(f << 14) + pos] = n;
    }
}

// ============ kernel E: new_cluster_size + smoothed ============
__global__ __launch_bounds__(256) void vq_smooth(const float* __restrict__ ecs,
                                                 const float* __restrict__ counts,
                                                 float* __restrict__ smoothed,
                                                 float* __restrict__ out) {
    __shared__ float wsum[4];
    const int f = blockIdx.x, tid = threadIdx.x;
    float v[2];
    float local = 0.f;
#pragma unroll
    for (int j = 0; j < 2; ++j) {
        int k = tid + j * 256;
        float c = counts[(size_t)f * NK + k];
        float nv = 0.99f * ecs[(size_t)f * NK + k] + 0.01f * c;
        out[NCS_OFF + (size_t)f * NK + k] = nv;
        v[j] = nv;
        local += nv;
    }
#pragma unroll
    for (int off = 32; off > 0; off >>= 1) local += __shfl_xor(local, off);
    if ((tid & 63) == 0) wsum[tid >> 6] = local;
    __syncthreads();
    float n = wsum[0] + wsum[1] + wsum[2] + wsum[3];
#pragma unroll
    for (int j = 0; j < 2; ++j) {
        int k = tid + j * 256;
        smoothed[(size_t)f * NK + k] = (v[j] + 1e-5f) / (n + (float)NK * 1e-5f) * n;
    }
}

// ============ kernel F: per-cluster pass: quantized write + loss + dw sum
//                        + fused EMA outputs ============
// grid: NF*NK blocks (one per (f,k)), 256 threads = 4 waves x 64 d-lanes
__global__ __launch_bounds__(256) void vq_dwsum(const float* __restrict__ x,
                                                const float* __restrict__ w,
                                                const int* __restrict__ sorted,
                                                const int* __restrict__ offs,
                                                const float* __restrict__ counts,
                                                const float* __restrict__ emaw,
                                                const float* __restrict__ smoothed,
                                                float* __restrict__ loss_sum,
                                                float* __restrict__ out) {
    __shared__ float part[4][64];
    __shared__ float lred[4];
    const int b = blockIdx.x;          // f*NK + k
    const int f = b >> 9;
    const int k = b & (NK - 1);
    const int wid = threadIdx.x >> 6;
    const int d = threadIdx.x & 63;

    const float wc = w[(size_t)f * NDK + (size_t)d * NK + k];  // codeword elem

    const int off = offs[b];
    const int cnt = (int)counts[b];
    const float* xf = x + ((size_t)f << 14) * ND;
    float* qf = out + ((size_t)f << 14) * ND;      // quantized region
    const int* sl = sorted + ((size_t)f << 14) + off;

    int per = (cnt + 3) >> 2;
    int t0 = wid * per;
    int t1 = t0 + per; if (t1 > cnt) t1 = cnt; if (t0 > cnt) t0 = cnt;

    float a = 0.f, l = 0.f;
    for (int t = t0; t < t1; ++t) {
        int n = sl[t];
        float xv = xf[(size_t)n * ND + d];
        a += xv;
        float df = wc - xv;
        l = fmaf(df, df, l);
        qf[(size_t)n * ND + d] = wc;               // quantized = codeword
    }
    part[wid][d] = a;
#pragma unroll
    for (int o = 32; o > 0; o >>= 1) l += __shfl_xor(l, o);
    if (d == 0) lred[wid] = l;
    __syncthreads();

    if (wid == 0) {
        float dwv = part[0][d] + part[1][d] + part[2][d] + part[3][d];
        size_t idx = (size_t)f * NDK + (size_t)d * NK + k;
        float ne = 0.99f * emaw[idx] + 0.01f * dwv;
        out[NEMA_OFF + idx] = ne;
        out[NEWW_OFF + idx] = ne / smoothed[b];
        if (d == 0)
            atomicAdd(loss_sum, lred[0] + lred[1] + lred[2] + lred[3]);
    }
}

// ============ kernel G: loss scalar ============
__global__ void vq_lossfin(const float* __restrict__ loss_sum,
                           float* __restrict__ out) {
    out[LOSS_OFF] = 0.25f * loss_sum[0] / (float)((size_t)NF * NT * ND);
}

extern "C" void kernel_launch(void* const* d_in, const int* in_sizes, int n_in,
                              void* d_out, int out_size, void* d_ws, size_t ws_size,
                              hipStream_t stream) {
    const float* x    = (const float*)d_in[0];
    const float* w    = (const float*)d_in[1];
    const float* ecs  = (const float*)d_in[2];
    const float* emaw = (const float*)d_in[3];
    float* out = (float*)d_out;
    float* ws  = (float*)d_ws;

    float* counts = ws + WS_CNT;
    float* loss   = ws + WS_LOSS;
    float* t      = ws + WS_T;
    float* sm     = ws + WS_SM;
    int*   offs   = (int*)(ws + WS_OFFS);
    int*   cursor = (int*)(ws + WS_CUR);
    int*   enc    = (int*)(ws + WS_ENC);
    int*   sorted = (int*)(ws + WS_SORT);

    // zero counts + loss (capture-safe)
    hipMemsetAsync(counts, 0, (size_t)4112 * sizeof(float), stream);

    vq_tsq<<<16, 256, 0, stream>>>(w, t);
    vq_assign<<<NF * 128, 256, 0, stream>>>(x, w, t, enc, counts);
    vq_scan<<<NF, 256, 0, stream>>>(counts, offs, cursor);
    vq_scatter<<<NFN / 256, 256, 0, stream>>>(enc, cursor, sorted);
    vq_smooth<<<NF, 256, 0, stream>>>(ecs, counts, sm, out);
    vq_dwsum<<<NF * NK, 256, 0, stream>>>(x, w, sorted, offs, counts, emaw, sm,
                                          loss, out);
    vq_lossfin<<<1, 1, 0, stream>>>(loss, out);
}

// Round 7
// 341.676 us; speedup vs baseline: 2.3808x; 1.0213x over previous
//
#include <hip/hip_runtime.h>
#include <cstddef>

#define NF 8
#define NT 16384
#define ND 64
#define NK 512
#define NDK (ND * NK)      // 32768
#define NFN (NF * NT)      // 131072
#define MARGIN 0.125f

typedef __attribute__((ext_vector_type(8))) short bf16x8;
typedef __attribute__((ext_vector_type(4))) float f32x4;
typedef unsigned int uint32;
typedef unsigned short ushort16;

// ---- workspace layout (float units) ----
static const size_t WS_CNT   = 0;        // counts      : 4096
static const size_t WS_LOSS  = 4096;     // loss accum  : 1
static const size_t WS_FLAGC = 4097;     // flag count  : 1 int
static const size_t WS_T     = 4112;     // tsq + 1024  : 4096
static const size_t WS_SM    = 8208;     // smoothed    : 4096
static const size_t WS_OFFS  = 12304;    // offsets     : 4096 ints
static const size_t WS_CUR   = 16400;    // cursors     : 4096 ints
static const size_t WS_ENC   = 20496;    // enc idx     : NFN ints
static const size_t WS_SORT  = 151568;   // sorted tok  : NFN ints
static const size_t WS_FLAGL = 282640;   // flag list   : NFN ints
static const size_t WS_WTH   = 413712;   // w^T hi bf16 : NF*NK*ND ushort = 131072 floats
static const size_t WS_WTL   = 544784;   // w^T lo bf16 : 131072 floats

// ---- output layout (float units) ----
static const size_t LOSS_OFF = (size_t)NF * NT * ND;        // 8388608
static const size_t NEWW_OFF = LOSS_OFF + 1;                // 8388609
static const size_t NCS_OFF  = NEWW_OFF + (size_t)NF * NDK; // 8650753
static const size_t NEMA_OFF = NCS_OFF + (size_t)NF * NK;   // 8654849

__device__ inline uint32 bfrne(float f) {   // round-to-nearest-even bf16, as hi-16 bits of f32
    uint32 u = __float_as_uint(f);
    return (u + 0x7FFFu + ((u >> 16) & 1u)) & 0xFFFF0000u;
}
__device__ inline uint32 umin_(uint32 a, uint32 b) { return a < b ? a : b; }
__device__ inline uint32 umax_(uint32 a, uint32 b) { return a > b ? a : b; }

// ============ kernel A: split W -> wt_hi/wt_lo [f,k,d] bf16 + tsq+1024 ============
__global__ __launch_bounds__(256) void vq_prep_w(const float* __restrict__ w,
                                                 ushort16* __restrict__ wth,
                                                 ushort16* __restrict__ wtl,
                                                 float* __restrict__ tsq) {
    int g = blockIdx.x * 256 + threadIdx.x;   // f*NK + k
    int f = g >> 9;
    int k = g & (NK - 1);
    const float* wf = w + (size_t)f * NDK + k;
    ushort16* ph = wth + (size_t)g * ND;
    ushort16* pl = wtl + (size_t)g * ND;
    float s = 0.f;
#pragma unroll
    for (int dc = 0; dc < 16; ++dc) {
        ushort16 h[4], lo[4];
#pragma unroll
        for (int i = 0; i < 4; ++i) {
            float vv = wf[(size_t)(dc * 4 + i) * NK];
            s = fmaf(vv, vv, s);
            uint32 hb = bfrne(vv);
            h[i] = (ushort16)(hb >> 16);
            float lf = vv - __uint_as_float(hb);
            lo[i] = (ushort16)(bfrne(lf) >> 16);
        }
        *reinterpret_cast<ushort4*>(ph + dc * 4) = make_ushort4(h[0], h[1], h[2], h[3]);
        *reinterpret_cast<ushort4*>(pl + dc * 4) = make_ushort4(lo[0], lo[1], lo[2], lo[3]);
    }
    tsq[g] = s + 1024.0f;   // bias: keys positive -> monotone uint compare
}

// ============ kernel B: MFMA argmin assignment ============
// block 256 = 4 independent waves; wave handles 64 tokens (4 groups of 16).
// C[k_row, token_col] = sum_d Wt[k,d] * X[token,d] via 16x16x32 bf16 MFMA,
// split-bf16 3-term decomposition. Per-lane packed-key top-2 argmin.
// Key low 9 bits embed (kt<<4 | q<<2 | r); any order corruption from the
// 9-bit truncation implies top-2 gap < 0.0625 < MARGIN -> exact fallback.
__global__ __launch_bounds__(256) void vq_assign(
    const float* __restrict__ x,
    const ushort16* __restrict__ wth, const ushort16* __restrict__ wtl,
    const float* __restrict__ tsq,
    int* __restrict__ enc, float* __restrict__ counts,
    int* __restrict__ flagcnt, int* __restrict__ flaglist) {
    const int tid = threadIdx.x;
    const int wv  = tid >> 6;
    const int l   = tid & 63;
    const int q   = l >> 4;      // k-quarter / d-chunk selector
    const int col = l & 15;      // token col (B) / k row (A)
    const int blk = blockIdx.x;
    const int f   = blk >> 6;                    // 64 blocks per feature
    const int n0  = (blk & 63) * 256 + wv * 64;  // wave's first token

    const float* xf = x + ((size_t)f * NT + n0) * ND;

    // ---- load + split-convert B fragments (64 tokens, resident in regs) ----
    bf16x8 bh[4][2], bl[4][2];
#pragma unroll
    for (int g = 0; g < 4; ++g)
#pragma unroll
        for (int s = 0; s < 2; ++s) {
            const float* p = xf + (size_t)(g * 16 + col) * ND + s * 32 + q * 8;
            f32x4 v0 = *reinterpret_cast<const f32x4*>(p);
            f32x4 v1 = *reinterpret_cast<const f32x4*>(p + 4);
            bf16x8 hh, ll;
#pragma unroll
            for (int j = 0; j < 4; ++j) {
                uint32 hb = bfrne(v0[j]);
                hh[j] = (short)(hb >> 16);
                ll[j] = (short)(bfrne(v0[j] - __uint_as_float(hb)) >> 16);
            }
#pragma unroll
            for (int j = 0; j < 4; ++j) {
                uint32 hb = bfrne(v1[j]);
                hh[4 + j] = (short)(hb >> 16);
                ll[4 + j] = (short)(bfrne(v1[j] - __uint_as_float(hb)) >> 16);
            }
            bh[g][s] = hh;
            bl[g][s] = ll;
        }

    uint32 u1[4], u2[4];
#pragma unroll
    for (int g = 0; g < 4; ++g) { u1[g] = 0xFFFFFFFFu; u2[g] = 0xFFFFFFFFu; }

    const ushort16* whf = wth + (size_t)f * NK * ND;
    const ushort16* wlf = wtl + (size_t)f * NK * ND;
    const float* tf = tsq + (size_t)f * NK;
    const int arow = col * ND + q * 8;

    for (int kt = 0; kt < 32; ++kt) {
        const ushort16* pa = whf + (size_t)kt * 16 * ND + arow;
        const ushort16* pb = wlf + (size_t)kt * 16 * ND + arow;
        bf16x8 ah0 = *reinterpret_cast<const bf16x8*>(pa);
        bf16x8 ah1 = *reinterpret_cast<const bf16x8*>(pa + 32);
        bf16x8 al0 = *reinterpret_cast<const bf16x8*>(pb);
        bf16x8 al1 = *reinterpret_cast<const bf16x8*>(pb + 32);
        f32x4 t4 = *reinterpret_cast<const f32x4*>(tf + kt * 16 + q * 4);
        uint32 lowb = ((uint32)kt << 4) | ((uint32)q << 2);
#pragma unroll
        for (int g = 0; g < 4; ++g) {
            f32x4 acc = {0.f, 0.f, 0.f, 0.f};
            acc = __builtin_amdgcn_mfma_f32_16x16x32_bf16(ah0, bh[g][0], acc, 0, 0, 0);
            acc = __builtin_amdgcn_mfma_f32_16x16x32_bf16(ah1, bh[g][1], acc, 0, 0, 0);
            acc = __builtin_amdgcn_mfma_f32_16x16x32_bf16(al0, bh[g][0], acc, 0, 0, 0);
            acc = __builtin_amdgcn_mfma_f32_16x16x32_bf16(al1, bh[g][1], acc, 0, 0, 0);
            acc = __builtin_amdgcn_mfma_f32_16x16x32_bf16(ah0, bl[g][0], acc, 0, 0, 0);
            acc = __builtin_amdgcn_mfma_f32_16x16x32_bf16(ah1, bl[g][1], acc, 0, 0, 0);
#pragma unroll
            for (int r = 0; r < 4; ++r) {
                float keyf = fmaf(-2.f, acc[r], t4[r]);          // dist + 1024 > 0
                uint32 key = (__float_as_uint(keyf) & 0xFFFFFE00u) | lowb | (uint32)r;
                uint32 mx = umax_(u1[g], key);
                u1[g] = umin_(u1[g], key);
                u2[g] = umin_(u2[g], mx);
            }
        }
    }

    // merge the 4 k-quarters (lanes xor 16, 32): top-2 merge
#pragma unroll
    for (int off = 16; off <= 32; off <<= 1)
#pragma unroll
        for (int g = 0; g < 4; ++g) {
            uint32 p1 = (uint32)__shfl_xor((int)u1[g], off);
            uint32 p2 = (uint32)__shfl_xor((int)u2[g], off);
            uint32 mx = umax_(u1[g], p1);
            u1[g] = umin_(u1[g], p1);
            u2[g] = umin_(umin_(u2[g], p2), mx);
        }

    if (l < 16) {
#pragma unroll
        for (int g = 0; g < 4; ++g) {
            uint32 m1 = u1[g], m2 = u2[g];
            int k = (int)(((m1 >> 4) & 31u) * 16u + ((m1 >> 2) & 3u) * 4u + (m1 & 3u));
            int n = n0 + g * 16 + l;
            enc[(size_t)f * NT + n] = k;
            atomicAdd(&counts[(size_t)f * NK + k], 1.0f);
            float d1 = __uint_as_float(m1 & 0xFFFFFE00u);
            float d2 = __uint_as_float(m2 & 0xFFFFFE00u);
            if (d2 - d1 < MARGIN) {
                int pos = atomicAdd(flagcnt, 1);
                flaglist[pos] = (f << 14) | n;
            }
        }
    }
}

// ============ kernel B2: exact f32 recheck for margin-flagged tokens ============
__global__ __launch_bounds__(64) void vq_fix(const float* __restrict__ x,
                                             const float* __restrict__ w,
                                             const int* __restrict__ flagcnt,
                                             const int* __restrict__ flaglist,
                                             int* __restrict__ enc,
                                             float* __restrict__ counts) {
    const int lane = threadIdx.x;
    const int cnt = flagcnt[0];
    for (int i = blockIdx.x; i < cnt; i += gridDim.x) {
        int code = flaglist[i];
        int f = code >> 14, n = code & (NT - 1);
        const float* xr = x + ((size_t)f * NT + n) * ND;
        const float* wf = w + (size_t)f * NDK;
        float best = 1e30f;
        int bk = 1 << 30;
#pragma unroll
        for (int j = 0; j < 8; ++j) {
            int k = j * 64 + lane;
            float s = 0.f;
#pragma unroll 8
            for (int d = 0; d < ND; ++d) {
                float diff = xr[d] - wf[(size_t)d * NK + k];
                s = fmaf(diff, diff, s);
            }
            if (s < best) { best = s; bk = k; }   // k ascending -> first-min
        }
#pragma unroll
        for (int off = 1; off < 64; off <<= 1) {
            float ov = __shfl_xor(best, off);
            int   oi = __shfl_xor(bk, off);
            if (ov < best || (ov == best && oi < bk)) { best = ov; bk = oi; }
        }
        if (lane == 0) {
            int kold = enc[(size_t)f * NT + n];
            if (kold != bk) {
                enc[(size_t)f * NT + n] = bk;
                atomicAdd(&counts[(size_t)f * NK + kold], -1.0f);
                atomicAdd(&counts[(size_t)f * NK + bk], 1.0f);
            }
        }
    }
}

// ============ kernel C: per-feature exclusive scan of counts ============
__global__ __launch_bounds__(256) void vq_scan(const float* __restrict__ counts,
                                               int* __restrict__ offs,
                                               int* __restrict__ cursor) {
    __shared__ int wsum[4];
    __shared__ int wpre[4];
    const int f = blockIdx.x, tid = threadIdx.x;
    int c0 = (int)counts[(size_t)f * NK + 2 * tid];
    int c1 = (int)counts[(size_t)f * NK + 2 * tid + 1];
    int pair = c0 + c1;
    int s = pair;
    int lane = tid & 63, wid = tid >> 6;
#pragma unroll
    for (int off = 1; off < 64; off <<= 1) {
        int v = __shfl_up(s, off);
        if (lane >= off) s += v;
    }
    if (lane == 63) wsum[wid] = s;
    __syncthreads();
    if (tid == 0) {
        int r = 0;
#pragma unroll
        for (int i = 0; i < 4; ++i) { wpre[i] = r; r += wsum[i]; }
    }
    __syncthreads();
    int excl = wpre[wid] + s - pair;
    int i0 = f * NK + 2 * tid;
    offs[i0] = excl;        offs[i0 + 1] = excl + c0;
    cursor[i0] = excl;      cursor[i0 + 1] = excl + c0;
}

// ============ kernel D: scatter token ids into cluster-sorted order ============
__global__ __launch_bounds__(256) void vq_scatter(const int* __restrict__ enc,
                                                  int* __restrict__ cursor,
                                                  int* __restrict__ sorted) {
    int i = blockIdx.x * 256 + threadIdx.x;
    if (i < NFN) {
        int f = i >> 14;
        int n = i & (NT - 1);
        int k = enc[i];
        int pos = atomicAdd(&cursor[f * NK + k], 1);
        sorted[(f << 14) + pos] = n;
    }
}

// ============ kernel E: new_cluster_size + smoothed ============
__global__ __launch_bounds__(256) void vq_smooth(const float* __restrict__ ecs,
                                                 const float* __restrict__ counts,
                                                 float* __restrict__ smoothed,
                                                 float* __restrict__ out) {
    __shared__ float wsum[4];
    const int f = blockIdx.x, tid = threadIdx.x;
    float v[2];
    float local = 0.f;
#pragma unroll
    for (int j = 0; j < 2; ++j) {
        int k = tid + j * 256;
        float c = counts[(size_t)f * NK + k];
        float nv = 0.99f * ecs[(size_t)f * NK + k] + 0.01f * c;
        out[NCS_OFF + (size_t)f * NK + k] = nv;
        v[j] = nv;
        local += nv;
    }
#pragma unroll
    for (int off = 32; off > 0; off >>= 1) local += __shfl_xor(local, off);
    if ((tid & 63) == 0) wsum[tid >> 6] = local;
    __syncthreads();
    float n = wsum[0] + wsum[1] + wsum[2] + wsum[3];
#pragma unroll
    for (int j = 0; j < 2; ++j) {
        int k = tid + j * 256;
        smoothed[(size_t)f * NK + k] = (v[j] + 1e-5f) / (n + (float)NK * 1e-5f) * n;
    }
}

// ============ kernel F: per-cluster pass: quantized write + loss + dw sum
//                        + fused EMA outputs ============
__global__ __launch_bounds__(256) void vq_dwsum(const float* __restrict__ x,
                                                const float* __restrict__ w,
                                                const int* __restrict__ sorted,
                                                const int* __restrict__ offs,
                                                const float* __restrict__ counts,
                                                const float* __restrict__ emaw,
                                                const float* __restrict__ smoothed,
                                                float* __restrict__ loss_sum,
                                                float* __restrict__ out) {
    __shared__ float part[4][64];
    __shared__ float lred[4];
    const int b = blockIdx.x;          // f*NK + k
    const int f = b >> 9;
    const int k = b & (NK - 1);
    const int wid = threadIdx.x >> 6;
    const int d = threadIdx.x & 63;

    const float wc = w[(size_t)f * NDK + (size_t)d * NK + k];

    const int off = offs[b];
    const int cnt = (int)counts[b];
    const float* xf = x + ((size_t)f << 14) * ND;
    float* qf = out + ((size_t)f << 14) * ND;
    const int* sl = sorted + ((size_t)f << 14) + off;

    int per = (cnt + 3) >> 2;
    int t0 = wid * per;
    int t1 = t0 + per; if (t1 > cnt) t1 = cnt; if (t0 > cnt) t0 = cnt;

    float a = 0.f, l = 0.f;
    for (int t = t0; t < t1; ++t) {
        int n = sl[t];
        float xv = xf[(size_t)n * ND + d];
        a += xv;
        float df = wc - xv;
        l = fmaf(df, df, l);
        qf[(size_t)n * ND + d] = wc;
    }
    part[wid][d] = a;
#pragma unroll
    for (int o = 32; o > 0; o >>= 1) l += __shfl_xor(l, o);
    if (d == 0) lred[wid] = l;
    __syncthreads();

    if (wid == 0) {
        float dwv = part[0][d] + part[1][d] + part[2][d] + part[3][d];
        size_t idx = (size_t)f * NDK + (size_t)d * NK + k;
        float ne = 0.99f * emaw[idx] + 0.01f * dwv;
        out[NEMA_OFF + idx] = ne;
        out[NEWW_OFF + idx] = ne / smoothed[b];
        if (d == 0)
            atomicAdd(loss_sum, lred[0] + lred[1] + lred[2] + lred[3]);
    }
}

// ============ kernel G: loss scalar ============
__global__ void vq_lossfin(const float* __restrict__ loss_sum,
                           float* __restrict__ out) {
    out[LOSS_OFF] = 0.25f * loss_sum[0] / (float)((size_t)NF * NT * ND);
}

extern "C" void kernel_launch(void* const* d_in, const int* in_sizes, int n_in,
                              void* d_out, int out_size, void* d_ws, size_t ws_size,
                              hipStream_t stream) {
    const float* x    = (const float*)d_in[0];
    const float* w    = (const float*)d_in[1];
    const float* ecs  = (const float*)d_in[2];
    const float* emaw = (const float*)d_in[3];
    float* out = (float*)d_out;
    float* ws  = (float*)d_ws;

    float*    counts  = ws + WS_CNT;
    float*    loss    = ws + WS_LOSS;
    int*      flagcnt = (int*)(ws + WS_FLAGC);
    float*    tsq     = ws + WS_T;
    float*    sm      = ws + WS_SM;
    int*      offs    = (int*)(ws + WS_OFFS);
    int*      cursor  = (int*)(ws + WS_CUR);
    int*      enc     = (int*)(ws + WS_ENC);
    int*      sorted  = (int*)(ws + WS_SORT);
    int*      flagl   = (int*)(ws + WS_FLAGL);
    ushort16* wth     = (ushort16*)(ws + WS_WTH);
    ushort16* wtl     = (ushort16*)(ws + WS_WTL);

    // zero counts + loss + flagcnt (capture-safe)
    hipMemsetAsync(counts, 0, (size_t)4112 * sizeof(float), stream);

    vq_prep_w<<<16, 256, 0, stream>>>(w, wth, wtl, tsq);
    vq_assign<<<NFN / 256, 256, 0, stream>>>(x, wth, wtl, tsq, enc, counts,
                                             flagcnt, flagl);
    vq_fix<<<512, 64, 0, stream>>>(x, w, flagcnt, flagl, enc, counts);
    vq_scan<<<NF, 256, 0, stream>>>(counts, offs, cursor);
    vq_scatter<<<NFN / 256, 256, 0, stream>>>(enc, cursor, sorted);
    vq_smooth<<<NF, 256, 0, stream>>>(ecs, counts, sm, out);
    vq_dwsum<<<NF * NK, 256, 0, stream>>>(x, w, sorted, offs, counts, emaw, sm,
                                          loss, out);
    vq_lossfin<<<1, 1, 0, stream>>>(loss, out);
}

// Round 9
// 260.396 us; speedup vs baseline: 3.1239x; 1.3121x over previous
//
#include <hip/hip_runtime.h>
#include <cstddef>

#define NF 8
#define NT 16384
#define ND 64
#define NK 512
#define NDK (ND * NK)      // 32768
#define NFN (NF * NT)      // 131072
#define MARGIN 0.125f

typedef __attribute__((ext_vector_type(8))) short bf16x8;
typedef __attribute__((ext_vector_type(4))) float f32x4;
typedef unsigned int uint32;
typedef unsigned short ushort16;

// ---- workspace layout (float units) ----
static const size_t WS_CNT   = 0;        // counts      : 4096
static const size_t WS_LOSS  = 4096;     // loss accum  : 1
static const size_t WS_FLAGC = 4097;     // flag count  : 1 int
static const size_t WS_T     = 4112;     // tsq + 1024  : 4096
static const size_t WS_SM    = 8208;     // smoothed    : 4096
static const size_t WS_OFFS  = 12304;    // offsets     : 4096 ints
static const size_t WS_CUR   = 16400;    // cursors     : 4096 ints
static const size_t WS_ENC   = 20496;    // enc idx     : NFN ints
static const size_t WS_SORT  = 151568;   // sorted tok  : NFN ints
static const size_t WS_FLAGL = 282640;   // flag list   : NFN ints
static const size_t WS_WTH   = 413712;   // w^T hi bf16 : 131072 floats
static const size_t WS_WTL   = 544784;   // w^T lo bf16 : 131072 floats
static const size_t WS_WT    = 675856;   // w^T f32 [f,k,d] : 262144 floats
static const size_t WS_DW    = 938000;   // dw accum    : 262144 floats

// ---- output layout (float units) ----
static const size_t LOSS_OFF = (size_t)NF * NT * ND;        // 8388608
static const size_t NEWW_OFF = LOSS_OFF + 1;                // 8388609
static const size_t NCS_OFF  = NEWW_OFF + (size_t)NF * NDK; // 8650753
static const size_t NEMA_OFF = NCS_OFF + (size_t)NF * NK;   // 8654849

__device__ inline uint32 bfrne(float f) {   // RNE bf16, as hi-16 bits of f32
    uint32 u = __float_as_uint(f);
    return (u + 0x7FFFu + ((u >> 16) & 1u)) & 0xFFFF0000u;
}
__device__ inline uint32 umin_(uint32 a, uint32 b) { return a < b ? a : b; }
__device__ inline uint32 umax_(uint32 a, uint32 b) { return a > b ? a : b; }

// ============ kernel A: W -> wt_hi/wt_lo bf16 [f,k,d] + wT f32 + tsq+1024 ============
__global__ __launch_bounds__(256) void vq_prep_w(const float* __restrict__ w,
                                                 ushort16* __restrict__ wth,
                                                 ushort16* __restrict__ wtl,
                                                 float* __restrict__ wT,
                                                 float* __restrict__ tsq) {
    int g = blockIdx.x * 256 + threadIdx.x;   // f*NK + k
    int f = g >> 9;
    int k = g & (NK - 1);
    const float* wf = w + (size_t)f * NDK + k;
    ushort16* ph = wth + (size_t)g * ND;
    ushort16* pl = wtl + (size_t)g * ND;
    float*    pt = wT + (size_t)g * ND;
    float s = 0.f;
#pragma unroll
    for (int dc = 0; dc < 16; ++dc) {
        ushort16 h[4], lo[4];
        float fv[4];
#pragma unroll
        for (int i = 0; i < 4; ++i) {
            float vv = wf[(size_t)(dc * 4 + i) * NK];
            fv[i] = vv;
            s = fmaf(vv, vv, s);
            uint32 hb = bfrne(vv);
            h[i] = (ushort16)(hb >> 16);
            float lf = vv - __uint_as_float(hb);
            lo[i] = (ushort16)(bfrne(lf) >> 16);
        }
        *reinterpret_cast<ushort4*>(ph + dc * 4) = make_ushort4(h[0], h[1], h[2], h[3]);
        *reinterpret_cast<ushort4*>(pl + dc * 4) = make_ushort4(lo[0], lo[1], lo[2], lo[3]);
        *reinterpret_cast<float4*>(pt + dc * 4) =
            make_float4(fv[0], fv[1], fv[2], fv[3]);
    }
    tsq[g] = s + 1024.0f;   // bias: keys positive -> monotone uint compare
}

// ============ kernel B: MFMA argmin assignment ============
// block 256 = 4 independent waves; wave handles 64 tokens (4 groups of 16).
// C[k_row, token_col] = sum_d Wt[k,d] * X[token,d] via 16x16x32 bf16 MFMA,
// split-bf16 3-term decomposition. Per-lane packed-key top-2 argmin.
// Key low 9 bits embed (kt<<4 | q<<2 | r); any order corruption from the
// 9-bit truncation implies top-2 gap < 0.0625 < MARGIN -> exact fallback.
__global__ __launch_bounds__(256) void vq_assign(
    const float* __restrict__ x,
    const ushort16* __restrict__ wth, const ushort16* __restrict__ wtl,
    const float* __restrict__ tsq,
    int* __restrict__ enc, float* __restrict__ counts,
    int* __restrict__ flagcnt, int* __restrict__ flaglist) {
    const int tid = threadIdx.x;
    const int wv  = tid >> 6;
    const int l   = tid & 63;
    const int q   = l >> 4;      // k-quarter / d-chunk selector
    const int col = l & 15;      // token col (B) / k row (A)
    const int blk = blockIdx.x;
    const int f   = blk >> 6;                    // 64 blocks per feature
    const int n0  = (blk & 63) * 256 + wv * 64;  // wave's first token

    const float* xf = x + ((size_t)f * NT + n0) * ND;

    // ---- load + split-convert B fragments (64 tokens, resident in regs) ----
    bf16x8 bh[4][2], bl[4][2];
#pragma unroll
    for (int g = 0; g < 4; ++g)
#pragma unroll
        for (int s = 0; s < 2; ++s) {
            const float* p = xf + (size_t)(g * 16 + col) * ND + s * 32 + q * 8;
            f32x4 v0 = *reinterpret_cast<const f32x4*>(p);
            f32x4 v1 = *reinterpret_cast<const f32x4*>(p + 4);
            bf16x8 hh, ll;
#pragma unroll
            for (int j = 0; j < 4; ++j) {
                uint32 hb = bfrne(v0[j]);
                hh[j] = (short)(hb >> 16);
                ll[j] = (short)(bfrne(v0[j] - __uint_as_float(hb)) >> 16);
            }
#pragma unroll
            for (int j = 0; j < 4; ++j) {
                uint32 hb = bfrne(v1[j]);
                hh[4 + j] = (short)(hb >> 16);
                ll[4 + j] = (short)(bfrne(v1[j] - __uint_as_float(hb)) >> 16);
            }
            bh[g][s] = hh;
            bl[g][s] = ll;
        }

    uint32 u1[4], u2[4];
#pragma unroll
    for (int g = 0; g < 4; ++g) { u1[g] = 0xFFFFFFFFu; u2[g] = 0xFFFFFFFFu; }

    const ushort16* whf = wth + (size_t)f * NK * ND;
    const ushort16* wlf = wtl + (size_t)f * NK * ND;
    const float* tf = tsq + (size_t)f * NK;
    const int arow = col * ND + q * 8;

    for (int kt = 0; kt < 32; ++kt) {
        const ushort16* pa = whf + (size_t)kt * 16 * ND + arow;
        const ushort16* pb = wlf + (size_t)kt * 16 * ND + arow;
        bf16x8 ah0 = *reinterpret_cast<const bf16x8*>(pa);
        bf16x8 ah1 = *reinterpret_cast<const bf16x8*>(pa + 32);
        bf16x8 al0 = *reinterpret_cast<const bf16x8*>(pb);
        bf16x8 al1 = *reinterpret_cast<const bf16x8*>(pb + 32);
        f32x4 t4 = *reinterpret_cast<const f32x4*>(tf + kt * 16 + q * 4);
        uint32 lowb = ((uint32)kt << 4) | ((uint32)q << 2);
#pragma unroll
        for (int g = 0; g < 4; ++g) {
            f32x4 acc = {0.f, 0.f, 0.f, 0.f};
            acc = __builtin_amdgcn_mfma_f32_16x16x32_bf16(ah0, bh[g][0], acc, 0, 0, 0);
            acc = __builtin_amdgcn_mfma_f32_16x16x32_bf16(ah1, bh[g][1], acc, 0, 0, 0);
            acc = __builtin_amdgcn_mfma_f32_16x16x32_bf16(al0, bh[g][0], acc, 0, 0, 0);
            acc = __builtin_amdgcn_mfma_f32_16x16x32_bf16(al1, bh[g][1], acc, 0, 0, 0);
            acc = __builtin_amdgcn_mfma_f32_16x16x32_bf16(ah0, bl[g][0], acc, 0, 0, 0);
            acc = __builtin_amdgcn_mfma_f32_16x16x32_bf16(ah1, bl[g][1], acc, 0, 0, 0);
#pragma unroll
            for (int r = 0; r < 4; ++r) {
                float keyf = fmaf(-2.f, acc[r], t4[r]);          // dist + 1024 > 0
                uint32 key = (__float_as_uint(keyf) & 0xFFFFFE00u) | lowb | (uint32)r;
                uint32 mx = umax_(u1[g], key);
                u1[g] = umin_(u1[g], key);
                u2[g] = umin_(u2[g], mx);
            }
        }
    }

    // merge the 4 k-quarters (lanes xor 16, 32): top-2 merge
#pragma unroll
    for (int off = 16; off <= 32; off <<= 1)
#pragma unroll
        for (int g = 0; g < 4; ++g) {
            uint32 p1 = (uint32)__shfl_xor((int)u1[g], off);
            uint32 p2 = (uint32)__shfl_xor((int)u2[g], off);
            uint32 mx = umax_(u1[g], p1);
            u1[g] = umin_(u1[g], p1);
            u2[g] = umin_(umin_(u2[g], p2), mx);
        }

    if (l < 16) {
#pragma unroll
        for (int g = 0; g < 4; ++g) {
            uint32 m1 = u1[g], m2 = u2[g];
            int k = (int)(((m1 >> 4) & 31u) * 16u + ((m1 >> 2) & 3u) * 4u + (m1 & 3u));
            int n = n0 + g * 16 + l;
            enc[(size_t)f * NT + n] = k;
            atomicAdd(&counts[(size_t)f * NK + k], 1.0f);
            float d1 = __uint_as_float(m1 & 0xFFFFFE00u);
            float d2 = __uint_as_float(m2 & 0xFFFFFE00u);
            if (d2 - d1 < MARGIN) {
                int pos = atomicAdd(flagcnt, 1);
                flaglist[pos] = (f << 14) | n;
            }
        }
    }
}

// ============ kernel B2: exact f32 recheck for margin-flagged tokens ============
__global__ __launch_bounds__(64) void vq_fix(const float* __restrict__ x,
                                             const float* __restrict__ w,
                                             const int* __restrict__ flagcnt,
                                             const int* __restrict__ flaglist,
                                             int* __restrict__ enc,
                                             float* __restrict__ counts) {
    const int lane = threadIdx.x;
    const int cnt = flagcnt[0];
    for (int i = blockIdx.x; i < cnt; i += gridDim.x) {
        int code = flaglist[i];
        int f = code >> 14, n = code & (NT - 1);
        const float* xr = x + ((size_t)f * NT + n) * ND;
        const float* wf = w + (size_t)f * NDK;
        float best = 1e30f;
        int bk = 1 << 30;
#pragma unroll
        for (int j = 0; j < 8; ++j) {
            int k = j * 64 + lane;
            float s = 0.f;
#pragma unroll 8
            for (int d = 0; d < ND; ++d) {
                float diff = xr[d] - wf[(size_t)d * NK + k];
                s = fmaf(diff, diff, s);
            }
            if (s < best) { best = s; bk = k; }   // k ascending -> first-min
        }
#pragma unroll
        for (int off = 1; off < 64; off <<= 1) {
            float ov = __shfl_xor(best, off);
            int   oi = __shfl_xor(bk, off);
            if (ov < best || (ov == best && oi < bk)) { best = ov; bk = oi; }
        }
        if (lane == 0) {
            int kold = enc[(size_t)f * NT + n];
            if (kold != bk) {
                enc[(size_t)f * NT + n] = bk;
                atomicAdd(&counts[(size_t)f * NK + kold], -1.0f);
                atomicAdd(&counts[(size_t)f * NK + bk], 1.0f);
            }
        }
    }
}

// ============ kernel C: per-feature exclusive scan of counts ============
__global__ __launch_bounds__(256) void vq_scan(const float* __restrict__ counts,
                                               int* __restrict__ offs,
                                               int* __restrict__ cursor) {
    __shared__ int wsum[4];
    __shared__ int wpre[4];
    const int f = blockIdx.x, tid = threadIdx.x;
    int c0 = (int)counts[(size_t)f * NK + 2 * tid];
    int c1 = (int)counts[(size_t)f * NK + 2 * tid + 1];
    int pair = c0 + c1;
    int s = pair;
    int lane = tid & 63, wid = tid >> 6;
#pragma unroll
    for (int off = 1; off < 64; off <<= 1) {
        int v = __shfl_up(s, off);
        if (lane >= off) s += v;
    }
    if (lane == 63) wsum[wid] = s;
    __syncthreads();
    if (tid == 0) {
        int r = 0;
#pragma unroll
        for (int i = 0; i < 4; ++i) { wpre[i] = r; r += wsum[i]; }
    }
    __syncthreads();
    int excl = wpre[wid] + s - pair;
    int i0 = f * NK + 2 * tid;
    offs[i0] = excl;        offs[i0 + 1] = excl + c0;
    cursor[i0] = excl;      cursor[i0 + 1] = excl + c0;
}

// ============ kernel D: scatter token ids into cluster-sorted order ============
__global__ __launch_bounds__(256) void vq_scatter(const int* __restrict__ enc,
                                                  int* __restrict__ cursor,
                                                  int* __restrict__ sorted) {
    int i = blockIdx.x * 256 + threadIdx.x;
    if (i < NFN) {
        int f = i >> 14;
        int n = i & (NT - 1);
        int k = enc[i];
        int pos = atomicAdd(&cursor[f * NK + k], 1);
        sorted[(f << 14) + pos] = n;
    }
}

// ============ kernel E: new_cluster_size + smoothed ============
__global__ __launch_bounds__(256) void vq_smooth(const float* __restrict__ ecs,
                                                 const float* __restrict__ counts,
                                                 float* __restrict__ smoothed,
                                                 float* __restrict__ out) {
    __shared__ float wsum[4];
    const int f = blockIdx.x, tid = threadIdx.x;
    float v[2];
    float local = 0.f;
#pragma unroll
    for (int j = 0; j < 2; ++j) {
        int k = tid + j * 256;
        float c = counts[(size_t)f * NK + k];
        float nv = 0.99f * ecs[(size_t)f * NK + k] + 0.01f * c;
        out[NCS_OFF + (size_t)f * NK + k] = nv;
        v[j] = nv;
        local += nv;
    }
#pragma unroll
    for (int off = 32; off > 0; off >>= 1) local += __shfl_xor(local, off);
    if ((tid & 63) == 0) wsum[tid >> 6] = local;
    __syncthreads();
    float n = wsum[0] + wsum[1] + wsum[2] + wsum[3];
#pragma unroll
    for (int j = 0; j < 2; ++j) {
        int k = tid + j * 256;
        smoothed[(size_t)f * NK + k] = (v[j] + 1e-5f) / (n + (float)NK * 1e-5f) * n;
    }
}

// ============ kernel F: equal-work chunk pass over sorted tokens ============
// 2048 chunks of 64 sorted positions; block 256 = 4 independent waves,
// one chunk per wave. Per token: quantized write + loss; per cluster
// segment: one 64-lane atomicAdd flush into dw.
__global__ __launch_bounds__(256) void vq_chunk(const float* __restrict__ x,
                                                const float* __restrict__ wT,
                                                const int* __restrict__ sorted,
                                                const int* __restrict__ enc,
                                                float* __restrict__ dw,
                                                float* __restrict__ loss_sum,
                                                float* __restrict__ out) {
    const int tid  = threadIdx.x;
    const int lane = tid & 63;
    const int cw   = blockIdx.x * 4 + (tid >> 6);   // chunk id 0..2047
    const int f    = cw >> 8;                        // 256 chunks/feature
    const int base = (cw & 255) * 64;

    const float* xf  = x + (((size_t)f << 14) * ND);
    const float* wtf = wT + (size_t)f * NK * ND;
    float* qf = out + (((size_t)f << 14) * ND);
    float* dwf = dw + (size_t)f * NDK + (size_t)lane * NK;

    // each lane pre-loads one (token, k) pair for the chunk
    int n_l = sorted[((size_t)f << 14) + base + lane];
    int k_l = enc[((size_t)f << 14) + n_l];

    float acc = 0.f, l = 0.f;
    int kcur = __shfl(k_l, 0);
#pragma unroll 4
    for (int i = 0; i < 64; ++i) {
        int n = __shfl(n_l, i);
        int k = __shfl(k_l, i);
        float xv = xf[(size_t)n * ND + lane];
        float wc = wtf[(size_t)k * ND + lane];
        qf[(size_t)n * ND + lane] = wc;
        float df = wc - xv;
        l = fmaf(df, df, l);
        if (k != kcur) {               // wave-uniform branch
            atomicAdd(dwf + kcur, acc);
            acc = 0.f;
            kcur = k;
        }
        acc += xv;
    }
    atomicAdd(dwf + kcur, acc);

    // wave loss reduction, one atomic per wave
#pragma unroll
    for (int o = 32; o > 0; o >>= 1) l += __shfl_xor(l, o);
    if (lane == 0) atomicAdd(loss_sum, l);
}

// ============ kernel G: EMA finalize (elementwise) ============
__global__ __launch_bounds__(256) void vq_finalize(const float* __restrict__ dw,
                                                   const float* __restrict__ emaw,
                                                   const float* __restrict__ smoothed,
                                                   float* __restrict__ out) {
    int idx = blockIdx.x * 256 + threadIdx.x;   // 0 .. NF*NDK
    int f = idx >> 15;                           // NDK = 2^15
    int k = idx & (NK - 1);
    float ne = 0.99f * emaw[idx] + 0.01f * dw[idx];
    out[NEMA_OFF + idx] = ne;
    out[NEWW_OFF + idx] = ne / smoothed[(size_t)f * NK + k];
}

// ============ kernel H: loss scalar ============
__global__ void vq_lossfin(const float* __restrict__ loss_sum,
                           float* __restrict__ out) {
    out[LOSS_OFF] = 0.25f * loss_sum[0] / (float)((size_t)NF * NT * ND);
}

extern "C" void kernel_launch(void* const* d_in, const int* in_sizes, int n_in,
                              void* d_out, int out_size, void* d_ws, size_t ws_size,
                              hipStream_t stream) {
    const float* x    = (const float*)d_in[0];
    const float* w    = (const float*)d_in[1];
    const float* ecs  = (const float*)d_in[2];
    const float* emaw = (const float*)d_in[3];
    float* out = (float*)d_out;
    float* ws  = (float*)d_ws;

    float*    counts  = ws + WS_CNT;
    float*    loss    = ws + WS_LOSS;
    int*      flagcnt = (int*)(ws + WS_FLAGC);
    float*    tsq     = ws + WS_T;
    float*    sm      = ws + WS_SM;
    int*      offs    = (int*)(ws + WS_OFFS);
    int*      cursor  = (int*)(ws + WS_CUR);
    int*      enc     = (int*)(ws + WS_ENC);
    int*      sorted  = (int*)(ws + WS_SORT);
    int*      flagl   = (int*)(ws + WS_FLAGL);
    ushort16* wth     = (ushort16*)(ws + WS_WTH);
    ushort16* wtl     = (ushort16*)(ws + WS_WTL);
    float*    wT      = ws + WS_WT;
    float*    dw      = ws + WS_DW;

    // zero counts + loss + flagcnt, and dw accumulator (capture-safe)
    hipMemsetAsync(counts, 0, (size_t)4112 * sizeof(float), stream);
    hipMemsetAsync(dw, 0, (size_t)NF * NDK * sizeof(float), stream);

    vq_prep_w<<<16, 256, 0, stream>>>(w, wth, wtl, wT, tsq);
    vq_assign<<<NFN / 256, 256, 0, stream>>>(x, wth, wtl, tsq, enc, counts,
                                             flagcnt, flagl);
    vq_fix<<<512, 64, 0, stream>>>(x, w, flagcnt, flagl, enc, counts);
    vq_scan<<<NF, 256, 0, stream>>>(counts, offs, cursor);
    vq_scatter<<<NFN / 256, 256, 0, stream>>>(enc, cursor, sorted);
    vq_smooth<<<NF, 256, 0, stream>>>(ecs, counts, sm, out);
    vq_chunk<<<512, 256, 0, stream>>>(x, wT, sorted, enc, dw, loss, out);
    vq_finalize<<<NF * NDK / 256, 256, 0, stream>>>(dw, emaw, sm, out);
    vq_lossfin<<<1, 1, 0, stream>>>(loss, out);
}

// Round 10
// 190.984 us; speedup vs baseline: 4.2593x; 1.3634x over previous
//
#include <hip/hip_runtime.h>
#include <cstddef>

#define NF 8
#define NT 16384
#define ND 64
#define NK 512
#define NDK (ND * NK)      // 32768
#define NFN (NF * NT)      // 131072
#define MARGIN 0.125f

typedef __attribute__((ext_vector_type(8))) short bf16x8;
typedef __attribute__((ext_vector_type(4))) float f32x4;
typedef unsigned int uint32;
typedef unsigned short ushort16;

// ---- workspace layout (float units) ----
static const size_t WS_CNT   = 0;        // counts      : 4096
static const size_t WS_LOSS  = 4096;     // loss accum  : 1
static const size_t WS_FLAGC = 4097;     // flag count  : 1 int
static const size_t WS_T     = 4112;     // tsq + 1024  : 4096
static const size_t WS_SM    = 8208;     // smoothed    : 4096
static const size_t WS_OFFS  = 12304;    // offsets     : 4096 ints
static const size_t WS_CUR   = 16400;    // cursors     : 4096 ints
static const size_t WS_ENC   = 20496;    // enc idx     : NFN ints
static const size_t WS_SORT  = 151568;   // sorted tok  : NFN ints
static const size_t WS_FLAGL = 282640;   // flag list   : NFN ints
static const size_t WS_WTH   = 413712;   // w^T hi bf16 : 131072 floats
static const size_t WS_WTL   = 544784;   // w^T lo bf16 : 131072 floats
static const size_t WS_WT    = 675856;   // w^T f32 [f,k,d] : 262144 floats
static const size_t WS_DW    = 938000;   // dw accum    : 262144 floats

// ---- output layout (float units) ----
static const size_t LOSS_OFF = (size_t)NF * NT * ND;        // 8388608
static const size_t NEWW_OFF = LOSS_OFF + 1;                // 8388609
static const size_t NCS_OFF  = NEWW_OFF + (size_t)NF * NDK; // 8650753
static const size_t NEMA_OFF = NCS_OFF + (size_t)NF * NK;   // 8654849

__device__ inline uint32 bfrne(float f) {   // RNE bf16, as hi-16 bits of f32
    uint32 u = __float_as_uint(f);
    return (u + 0x7FFFu + ((u >> 16) & 1u)) & 0xFFFF0000u;
}
__device__ inline uint32 umin_(uint32 a, uint32 b) { return a < b ? a : b; }
__device__ inline uint32 umax_(uint32 a, uint32 b) { return a > b ? a : b; }

// ============ kernel A: W -> wt_hi/wt_lo bf16 [f,k,d] + wT f32 + tsq+1024 ============
__global__ __launch_bounds__(256) void vq_prep_w(const float* __restrict__ w,
                                                 ushort16* __restrict__ wth,
                                                 ushort16* __restrict__ wtl,
                                                 float* __restrict__ wT,
                                                 float* __restrict__ tsq) {
    int g = blockIdx.x * 256 + threadIdx.x;   // f*NK + k
    int f = g >> 9;
    int k = g & (NK - 1);
    const float* wf = w + (size_t)f * NDK + k;
    ushort16* ph = wth + (size_t)g * ND;
    ushort16* pl = wtl + (size_t)g * ND;
    float*    pt = wT + (size_t)g * ND;
    float s = 0.f;
#pragma unroll
    for (int dc = 0; dc < 16; ++dc) {
        ushort16 h[4], lo[4];
        float fv[4];
#pragma unroll
        for (int i = 0; i < 4; ++i) {
            float vv = wf[(size_t)(dc * 4 + i) * NK];
            fv[i] = vv;
            s = fmaf(vv, vv, s);
            uint32 hb = bfrne(vv);
            h[i] = (ushort16)(hb >> 16);
            float lf = vv - __uint_as_float(hb);
            lo[i] = (ushort16)(bfrne(lf) >> 16);
        }
        *reinterpret_cast<ushort4*>(ph + dc * 4) = make_ushort4(h[0], h[1], h[2], h[3]);
        *reinterpret_cast<ushort4*>(pl + dc * 4) = make_ushort4(lo[0], lo[1], lo[2], lo[3]);
        *reinterpret_cast<float4*>(pt + dc * 4) =
            make_float4(fv[0], fv[1], fv[2], fv[3]);
    }
    tsq[g] = s + 1024.0f;   // bias: keys positive -> monotone uint compare
}

// ============ kernel B: MFMA argmin assignment ============
// block 256 = 4 independent waves; wave handles 64 tokens (4 groups of 16).
// C[k_row, token_col] = sum_d Wt[k,d] * X[token,d] via 16x16x32 bf16 MFMA,
// split-bf16 3-term decomposition. Per-lane packed-key top-2 argmin.
// Key low 9 bits embed (kt<<4 | q<<2 | r); any order corruption from the
// 9-bit truncation implies top-2 gap < 0.0625 < MARGIN -> exact fallback.
__global__ __launch_bounds__(256) void vq_assign(
    const float* __restrict__ x,
    const ushort16* __restrict__ wth, const ushort16* __restrict__ wtl,
    const float* __restrict__ tsq,
    int* __restrict__ enc, float* __restrict__ counts,
    int* __restrict__ flagcnt, int* __restrict__ flaglist) {
    const int tid = threadIdx.x;
    const int wv  = tid >> 6;
    const int l   = tid & 63;
    const int q   = l >> 4;      // k-quarter / d-chunk selector
    const int col = l & 15;      // token col (B) / k row (A)
    const int blk = blockIdx.x;
    const int f   = blk >> 6;                    // 64 blocks per feature
    const int n0  = (blk & 63) * 256 + wv * 64;  // wave's first token

    const float* xf = x + ((size_t)f * NT + n0) * ND;

    // ---- load + split-convert B fragments (64 tokens, resident in regs) ----
    bf16x8 bh[4][2], bl[4][2];
#pragma unroll
    for (int g = 0; g < 4; ++g)
#pragma unroll
        for (int s = 0; s < 2; ++s) {
            const float* p = xf + (size_t)(g * 16 + col) * ND + s * 32 + q * 8;
            f32x4 v0 = *reinterpret_cast<const f32x4*>(p);
            f32x4 v1 = *reinterpret_cast<const f32x4*>(p + 4);
            bf16x8 hh, ll;
#pragma unroll
            for (int j = 0; j < 4; ++j) {
                uint32 hb = bfrne(v0[j]);
                hh[j] = (short)(hb >> 16);
                ll[j] = (short)(bfrne(v0[j] - __uint_as_float(hb)) >> 16);
            }
#pragma unroll
            for (int j = 0; j < 4; ++j) {
                uint32 hb = bfrne(v1[j]);
                hh[4 + j] = (short)(hb >> 16);
                ll[4 + j] = (short)(bfrne(v1[j] - __uint_as_float(hb)) >> 16);
            }
            bh[g][s] = hh;
            bl[g][s] = ll;
        }

    uint32 u1[4], u2[4];
#pragma unroll
    for (int g = 0; g < 4; ++g) { u1[g] = 0xFFFFFFFFu; u2[g] = 0xFFFFFFFFu; }

    const ushort16* whf = wth + (size_t)f * NK * ND;
    const ushort16* wlf = wtl + (size_t)f * NK * ND;
    const float* tf = tsq + (size_t)f * NK;
    const int arow = col * ND + q * 8;

    for (int kt = 0; kt < 32; ++kt) {
        const ushort16* pa = whf + (size_t)kt * 16 * ND + arow;
        const ushort16* pb = wlf + (size_t)kt * 16 * ND + arow;
        bf16x8 ah0 = *reinterpret_cast<const bf16x8*>(pa);
        bf16x8 ah1 = *reinterpret_cast<const bf16x8*>(pa + 32);
        bf16x8 al0 = *reinterpret_cast<const bf16x8*>(pb);
        bf16x8 al1 = *reinterpret_cast<const bf16x8*>(pb + 32);
        f32x4 t4 = *reinterpret_cast<const f32x4*>(tf + kt * 16 + q * 4);
        uint32 lowb = ((uint32)kt << 4) | ((uint32)q << 2);
#pragma unroll
        for (int g = 0; g < 4; ++g) {
            f32x4 acc = {0.f, 0.f, 0.f, 0.f};
            acc = __builtin_amdgcn_mfma_f32_16x16x32_bf16(ah0, bh[g][0], acc, 0, 0, 0);
            acc = __builtin_amdgcn_mfma_f32_16x16x32_bf16(ah1, bh[g][1], acc, 0, 0, 0);
            acc = __builtin_amdgcn_mfma_f32_16x16x32_bf16(al0, bh[g][0], acc, 0, 0, 0);
            acc = __builtin_amdgcn_mfma_f32_16x16x32_bf16(al1, bh[g][1], acc, 0, 0, 0);
            acc = __builtin_amdgcn_mfma_f32_16x16x32_bf16(ah0, bl[g][0], acc, 0, 0, 0);
            acc = __builtin_amdgcn_mfma_f32_16x16x32_bf16(ah1, bl[g][1], acc, 0, 0, 0);
#pragma unroll
            for (int r = 0; r < 4; ++r) {
                float keyf = fmaf(-2.f, acc[r], t4[r]);          // dist + 1024 > 0
                uint32 key = (__float_as_uint(keyf) & 0xFFFFFE00u) | lowb | (uint32)r;
                uint32 mx = umax_(u1[g], key);
                u1[g] = umin_(u1[g], key);
                u2[g] = umin_(u2[g], mx);
            }
        }
    }

    // merge the 4 k-quarters (lanes xor 16, 32): top-2 merge
#pragma unroll
    for (int off = 16; off <= 32; off <<= 1)
#pragma unroll
        for (int g = 0; g < 4; ++g) {
            uint32 p1 = (uint32)__shfl_xor((int)u1[g], off);
            uint32 p2 = (uint32)__shfl_xor((int)u2[g], off);
            uint32 mx = umax_(u1[g], p1);
            u1[g] = umin_(u1[g], p1);
            u2[g] = umin_(umin_(u2[g], p2), mx);
        }

    if (l < 16) {
#pragma unroll
        for (int g = 0; g < 4; ++g) {
            uint32 m1 = u1[g], m2 = u2[g];
            int k = (int)(((m1 >> 4) & 31u) * 16u + ((m1 >> 2) & 3u) * 4u + (m1 & 3u));
            int n = n0 + g * 16 + l;
            enc[(size_t)f * NT + n] = k;
            atomicAdd(&counts[(size_t)f * NK + k], 1.0f);
            float d1 = __uint_as_float(m1 & 0xFFFFFE00u);
            float d2 = __uint_as_float(m2 & 0xFFFFFE00u);
            if (d2 - d1 < MARGIN) {
                int pos = atomicAdd(flagcnt, 1);
                flaglist[pos] = (f << 14) | n;
            }
        }
    }
}

// ============ kernel B2: exact f32 recheck for margin-flagged tokens ============
// block 256 = 4 independent waves; ONE TOKEN PER WAVE (was per 64-thread
// block -> 4.6% occupancy, 94 us). Grid 2048 blocks -> up to 8192 tokens
// in flight. Per-token algorithm unchanged.
__global__ __launch_bounds__(256) void vq_fix(const float* __restrict__ x,
                                              const float* __restrict__ w,
                                              const int* __restrict__ flagcnt,
                                              const int* __restrict__ flaglist,
                                              int* __restrict__ enc,
                                              float* __restrict__ counts) {
    const int lane = threadIdx.x & 63;
    const int wv   = threadIdx.x >> 6;
    const int cnt = flagcnt[0];
    const int stride = gridDim.x * 4;
    for (int i = blockIdx.x * 4 + wv; i < cnt; i += stride) {
        int code = flaglist[i];
        int f = code >> 14, n = code & (NT - 1);
        const float* xr = x + ((size_t)f * NT + n) * ND;
        const float* wf = w + (size_t)f * NDK;
        float best = 1e30f;
        int bk = 1 << 30;
#pragma unroll
        for (int j = 0; j < 8; ++j) {
            int k = j * 64 + lane;
            float s = 0.f;
#pragma unroll 8
            for (int d = 0; d < ND; ++d) {
                float diff = xr[d] - wf[(size_t)d * NK + k];
                s = fmaf(diff, diff, s);
            }
            if (s < best) { best = s; bk = k; }   // k ascending -> first-min
        }
#pragma unroll
        for (int off = 1; off < 64; off <<= 1) {
            float ov = __shfl_xor(best, off);
            int   oi = __shfl_xor(bk, off);
            if (ov < best || (ov == best && oi < bk)) { best = ov; bk = oi; }
        }
        if (lane == 0) {
            int kold = enc[(size_t)f * NT + n];
            if (kold != bk) {
                enc[(size_t)f * NT + n] = bk;
                atomicAdd(&counts[(size_t)f * NK + kold], -1.0f);
                atomicAdd(&counts[(size_t)f * NK + bk], 1.0f);
            }
        }
    }
}

// ============ kernel C: per-feature exclusive scan of counts ============
__global__ __launch_bounds__(256) void vq_scan(const float* __restrict__ counts,
                                               int* __restrict__ offs,
                                               int* __restrict__ cursor) {
    __shared__ int wsum[4];
    __shared__ int wpre[4];
    const int f = blockIdx.x, tid = threadIdx.x;
    int c0 = (int)counts[(size_t)f * NK + 2 * tid];
    int c1 = (int)counts[(size_t)f * NK + 2 * tid + 1];
    int pair = c0 + c1;
    int s = pair;
    int lane = tid & 63, wid = tid >> 6;
#pragma unroll
    for (int off = 1; off < 64; off <<= 1) {
        int v = __shfl_up(s, off);
        if (lane >= off) s += v;
    }
    if (lane == 63) wsum[wid] = s;
    __syncthreads();
    if (tid == 0) {
        int r = 0;
#pragma unroll
        for (int i = 0; i < 4; ++i) { wpre[i] = r; r += wsum[i]; }
    }
    __syncthreads();
    int excl = wpre[wid] + s - pair;
    int i0 = f * NK + 2 * tid;
    offs[i0] = excl;        offs[i0 + 1] = excl + c0;
    cursor[i0] = excl;      cursor[i0 + 1] = excl + c0;
}

// ============ kernel D: scatter token ids into cluster-sorted order ============
__global__ __launch_bounds__(256) void vq_scatter(const int* __restrict__ enc,
                                                  int* __restrict__ cursor,
                                                  int* __restrict__ sorted) {
    int i = blockIdx.x * 256 + threadIdx.x;
    if (i < NFN) {
        int f = i >> 14;
        int n = i & (NT - 1);
        int k = enc[i];
        int pos = atomicAdd(&cursor[f * NK + k], 1);
        sorted[(f << 14) + pos] = n;
    }
}

// ============ kernel E: new_cluster_size + smoothed ============
__global__ __launch_bounds__(256) void vq_smooth(const float* __restrict__ ecs,
                                                 const float* __restrict__ counts,
                                                 float* __restrict__ smoothed,
                                                 float* __restrict__ out) {
    __shared__ float wsum[4];
    const int f = blockIdx.x, tid = threadIdx.x;
    float v[2];
    float local = 0.f;
#pragma unroll
    for (int j = 0; j < 2; ++j) {
        int k = tid + j * 256;
        float c = counts[(size_t)f * NK + k];
        float nv = 0.99f * ecs[(size_t)f * NK + k] + 0.01f * c;
        out[NCS_OFF + (size_t)f * NK + k] = nv;
        v[j] = nv;
        local += nv;
    }
#pragma unroll
    for (int off = 32; off > 0; off >>= 1) local += __shfl_xor(local, off);
    if ((tid & 63) == 0) wsum[tid >> 6] = local;
    __syncthreads();
    float n = wsum[0] + wsum[1] + wsum[2] + wsum[3];
#pragma unroll
    for (int j = 0; j < 2; ++j) {
        int k = tid + j * 256;
        smoothed[(size_t)f * NK + k] = (v[j] + 1e-5f) / (n + (float)NK * 1e-5f) * n;
    }
}

// ============ kernel F: equal-work chunk pass over sorted tokens ============
// 2048 chunks of 64 sorted positions; block 256 = 4 independent waves,
// one chunk per wave. Per token: quantized write + loss; per cluster
// segment: one 64-lane atomicAdd flush into dw.
__global__ __launch_bounds__(256) void vq_chunk(const float* __restrict__ x,
                                                const float* __restrict__ wT,
                                                const int* __restrict__ sorted,
                                                const int* __restrict__ enc,
                                                float* __restrict__ dw,
                                                float* __restrict__ loss_sum,
                                                float* __restrict__ out) {
    const int tid  = threadIdx.x;
    const int lane = tid & 63;
    const int cw   = blockIdx.x * 4 + (tid >> 6);   // chunk id 0..2047
    const int f    = cw >> 8;                        // 256 chunks/feature
    const int base = (cw & 255) * 64;

    const float* xf  = x + (((size_t)f << 14) * ND);
    const float* wtf = wT + (size_t)f * NK * ND;
    float* qf = out + (((size_t)f << 14) * ND);
    float* dwf = dw + (size_t)f * NDK + (size_t)lane * NK;

    // each lane pre-loads one (token, k) pair for the chunk
    int n_l = sorted[((size_t)f << 14) + base + lane];
    int k_l = enc[((size_t)f << 14) + n_l];

    float acc = 0.f, l = 0.f;
    int kcur = __shfl(k_l, 0);
#pragma unroll 4
    for (int i = 0; i < 64; ++i) {
        int n = __shfl(n_l, i);
        int k = __shfl(k_l, i);
        float xv = xf[(size_t)n * ND + lane];
        float wc = wtf[(size_t)k * ND + lane];
        qf[(size_t)n * ND + lane] = wc;
        float df = wc - xv;
        l = fmaf(df, df, l);
        if (k != kcur) {               // wave-uniform branch
            atomicAdd(dwf + kcur, acc);
            acc = 0.f;
            kcur = k;
        }
        acc += xv;
    }
    atomicAdd(dwf + kcur, acc);

    // wave loss reduction, one atomic per wave
#pragma unroll
    for (int o = 32; o > 0; o >>= 1) l += __shfl_xor(l, o);
    if (lane == 0) atomicAdd(loss_sum, l);
}

// ============ kernel G: EMA finalize (elementwise) ============
__global__ __launch_bounds__(256) void vq_finalize(const float* __restrict__ dw,
                                                   const float* __restrict__ emaw,
                                                   const float* __restrict__ smoothed,
                                                   float* __restrict__ out) {
    int idx = blockIdx.x * 256 + threadIdx.x;   // 0 .. NF*NDK
    int f = idx >> 15;                           // NDK = 2^15
    int k = idx & (NK - 1);
    float ne = 0.99f * emaw[idx] + 0.01f * dw[idx];
    out[NEMA_OFF + idx] = ne;
    out[NEWW_OFF + idx] = ne / smoothed[(size_t)f * NK + k];
}

// ============ kernel H: loss scalar ============
__global__ void vq_lossfin(const float* __restrict__ loss_sum,
                           float* __restrict__ out) {
    out[LOSS_OFF] = 0.25f * loss_sum[0] / (float)((size_t)NF * NT * ND);
}

extern "C" void kernel_launch(void* const* d_in, const int* in_sizes, int n_in,
                              void* d_out, int out_size, void* d_ws, size_t ws_size,
                              hipStream_t stream) {
    const float* x    = (const float*)d_in[0];
    const float* w    = (const float*)d_in[1];
    const float* ecs  = (const float*)d_in[2];
    const float* emaw = (const float*)d_in[3];
    float* out = (float*)d_out;
    float* ws  = (float*)d_ws;

    float*    counts  = ws + WS_CNT;
    float*    loss    = ws + WS_LOSS;
    int*      flagcnt = (int*)(ws + WS_FLAGC);
    float*    tsq     = ws + WS_T;
    float*    sm      = ws + WS_SM;
    int*      offs    = (int*)(ws + WS_OFFS);
    int*      cursor  = (int*)(ws + WS_CUR);
    int*      enc     = (int*)(ws + WS_ENC);
    int*      sorted  = (int*)(ws + WS_SORT);
    int*      flagl   = (int*)(ws + WS_FLAGL);
    ushort16* wth     = (ushort16*)(ws + WS_WTH);
    ushort16* wtl     = (ushort16*)(ws + WS_WTL);
    float*    wT      = ws + WS_WT;
    float*    dw      = ws + WS_DW;

    // zero counts + loss + flagcnt, and dw accumulator (capture-safe)
    hipMemsetAsync(counts, 0, (size_t)4112 * sizeof(float), stream);
    hipMemsetAsync(dw, 0, (size_t)NF * NDK * sizeof(float), stream);

    vq_prep_w<<<16, 256, 0, stream>>>(w, wth, wtl, wT, tsq);
    vq_assign<<<NFN / 256, 256, 0, stream>>>(x, wth, wtl, tsq, enc, counts,
                                             flagcnt, flagl);
    vq_fix<<<2048, 256, 0, stream>>>(x, w, flagcnt, flagl, enc, counts);
    vq_scan<<<NF, 256, 0, stream>>>(counts, offs, cursor);
    vq_scatter<<<NFN / 256, 256, 0, stream>>>(enc, cursor, sorted);
    vq_smooth<<<NF, 256, 0, stream>>>(ecs, counts, sm, out);
    vq_chunk<<<512, 256, 0, stream>>>(x, wT, sorted, enc, dw, loss, out);
    vq_finalize<<<NF * NDK / 256, 256, 0, stream>>>(dw, emaw, sm, out);
    vq_lossfin<<<1, 1, 0, stream>>>(loss, out);
}